// Round 1
// baseline (8491.339 us; speedup 1.0000x reference)
//
#include <hip/hip_runtime.h>
#include <hip/hip_bf16.h>

// CGCNN forward, f32 correctness-first implementation.
// Structure per layer:
//   pass A (conv_pass<0>): recompute g = tot@W+b, accumulate per-channel sum/sumsq (bn1 stats)
//   fin1: fold bn1 stats+gamma/beta into scale/shift
//   pass B (conv_pass<1>): recompute g, apply bn1, sigmoid(filt)*softplus(core), sum over M
//                          -> summed (N,64); also accumulate bn2 stats
//   fin2: fold bn2 stats
//   update_x: x = softplus(x + bn2(summed))
// Then: segment mean-pool (atomics) + per-crystal head.

#define NN    100000
#define MM    12
#define ORIG  92
#define FF    64
#define NBR   41
#define HH    128
#define NCONV 3
#define CC    3125
#define K2    169      // 2F + NBR
#define KP    172      // K2 padded to multiple of 4
#define GG    128      // 2F
#define EPSV  1e-5f

__device__ __forceinline__ float softplusf(float v) {
    return fmaxf(v, 0.f) + log1pf(expf(-fabsf(v)));
}
__device__ __forceinline__ float sigmoidf_(float v) {
    return 1.f / (1.f + expf(-v));
}

// ---------------- embed: x = (atom_fea * mask) @ embW + embb ----------------
__global__ void embed_kernel(const float* __restrict__ af, const float* __restrict__ mask,
                             const float* __restrict__ embW, const float* __restrict__ embb,
                             float* __restrict__ x) {
    int t = threadIdx.x;
    int c = t & 63;          // feature
    int rs = t >> 6;         // 4 rows per block-iter
    float b = embb[c];
    for (int row = blockIdx.x * 4 + rs; row < NN; row += gridDim.x * 4) {
        float acc = b;
        for (int o = 0; o < ORIG; o++) {
            acc += af[row * ORIG + o] * (mask[o] * embW[o * FF + c]);
        }
        x[row * FF + c] = acc;
    }
}

// ---------------- pad fcW[l] (169x128) into Wpad (172x128, zero pad) ----------------
__global__ void padw_kernel(const float* __restrict__ fcW, int layer, float* __restrict__ Wpad) {
    int i = blockIdx.x * 256 + threadIdx.x;
    if (i < KP * GG) {
        int k = i / GG;
        Wpad[i] = (k < K2) ? fcW[layer * K2 * GG + i] : 0.f;
    }
}

// ---------------- conv GEMM pass ----------------
// PASS 0: bn1 stats (sum, sumsq per channel of g) -> stats[0..127], stats[128..255]
// PASS 1: apply bn1 (sc1/sh1), sigmoid*softplus, sum over M -> summed; bn2 stats -> stats2
template <int PASS>
__launch_bounds__(256)
__global__ void conv_pass(const float* __restrict__ x, const int* __restrict__ nidx,
                          const float* __restrict__ nbr_fea, const float* __restrict__ Wp,
                          const float* __restrict__ fcb_l,
                          float* __restrict__ stats,
                          const float* __restrict__ sc1, const float* __restrict__ sh1,
                          float* __restrict__ summed, float* __restrict__ stats2) {
    __shared__ __align__(16) float tl[24 * KP];   // 24 tot rows, padded
    __shared__ int nb[24];
    __shared__ float gbuf[24 * GG];               // PASS1: normalized g

    int t = threadIdx.x;
    int cg = t & 31;           // channel group: channels c0..c0+3
    int c0 = cg * 4;
    int pg = t >> 5;           // pair group 0..7, pairs pg*3..pg*3+2
    int prow = pg * 3;

    float bias[4], sc[4], sh[4];
#pragma unroll
    for (int q = 0; q < 4; q++) {
        bias[q] = fcb_l[c0 + q];
        if (PASS == 1) { sc[q] = sc1[c0 + q]; sh[q] = sh1[c0 + q]; }
    }

    float sA[4] = {0, 0, 0, 0}, sB[4] = {0, 0, 0, 0};  // PASS0 partials
    float s2a = 0.f, s2b = 0.f;                         // PASS1 bn2 partials (t<128)

    const float4* Wv = (const float4*)Wp;

    for (int ab = blockIdx.x; ab < NN / 2; ab += gridDim.x) {
        int atom0 = ab * 2;
        __syncthreads();  // protect tl/nb/gbuf from previous iteration
        if (t < 24) nb[t] = nidx[atom0 * MM + t];
        __syncthreads();
        // stage 24 tot rows: [x[a] | x[nbr] | nbr_fea], pad to KP with zeros
        for (int e = t; e < 24 * KP; e += 256) {
            int p = e / KP;
            int k = e - p * KP;
            int a1 = (p >= 12) ? 1 : 0;
            int atom = atom0 + a1;
            int pr = atom * MM + (p - a1 * 12);
            float v = 0.f;
            if (k < FF)           v = x[atom * FF + k];
            else if (k < 2 * FF)  v = x[nb[p] * FF + (k - FF)];
            else if (k < K2)      v = nbr_fea[pr * NBR + (k - 2 * FF)];
            tl[e] = v;
        }
        __syncthreads();

        float acc[3][4];
#pragma unroll
        for (int p = 0; p < 3; p++)
#pragma unroll
            for (int q = 0; q < 4; q++) acc[p][q] = bias[q];

        for (int k4 = 0; k4 < KP; k4 += 4) {
            float4 wv4[4];
#pragma unroll
            for (int i = 0; i < 4; i++) wv4[i] = Wv[(k4 + i) * 32 + cg];
            const float* w = (const float*)wv4;  // w[i*4+q]
#pragma unroll
            for (int p = 0; p < 3; p++) {
                float4 tv4 = *(const float4*)&tl[(prow + p) * KP + k4];
                float tv[4] = {tv4.x, tv4.y, tv4.z, tv4.w};
#pragma unroll
                for (int i = 0; i < 4; i++)
#pragma unroll
                    for (int q = 0; q < 4; q++)
                        acc[p][q] = fmaf(tv[i], w[i * 4 + q], acc[p][q]);
            }
        }

        if (PASS == 0) {
#pragma unroll
            for (int p = 0; p < 3; p++)
#pragma unroll
                for (int q = 0; q < 4; q++) {
                    float v = acc[p][q];
                    sA[q] += v;
                    sB[q] += v * v;
                }
        } else {
            // write normalized g to LDS
#pragma unroll
            for (int p = 0; p < 3; p++)
#pragma unroll
                for (int q = 0; q < 4; q++)
                    gbuf[(prow + p) * GG + c0 + q] = acc[p][q] * sc[q] + sh[q];
            __syncthreads();
            if (t < 128) {
                int aslot = t >> 6;
                int c = t & 63;
                float s = 0.f;
#pragma unroll
                for (int j = 0; j < MM; j++) {
                    float fv = gbuf[(aslot * MM + j) * GG + c];
                    float cv = gbuf[(aslot * MM + j) * GG + c + FF];
                    s += sigmoidf_(fv) * softplusf(cv);
                }
                summed[(atom0 + aslot) * FF + c] = s;
                s2a += s;
                s2b += s * s;
            }
        }
    }

    // ------- end-of-kernel block reductions -------
    if (PASS == 0) {
        __syncthreads();
#pragma unroll
        for (int q = 0; q < 4; q++) tl[t * 4 + q] = sA[q];
        __syncthreads();
        if (t < 32) {
#pragma unroll
            for (int q = 0; q < 4; q++) {
                float s = 0.f;
                for (int g2 = 0; g2 < 8; g2++) s += tl[(g2 * 32 + t) * 4 + q];
                atomicAdd(&stats[t * 4 + q], s);
            }
        }
        __syncthreads();
#pragma unroll
        for (int q = 0; q < 4; q++) tl[t * 4 + q] = sB[q];
        __syncthreads();
        if (t < 32) {
#pragma unroll
            for (int q = 0; q < 4; q++) {
                float s = 0.f;
                for (int g2 = 0; g2 < 8; g2++) s += tl[(g2 * 32 + t) * 4 + q];
                atomicAdd(&stats[128 + t * 4 + q], s);
            }
        }
    } else {
        __syncthreads();
        if (t < 128) { tl[t] = s2a; tl[128 + t] = s2b; }
        __syncthreads();
        if (t < 64) {
            atomicAdd(&stats2[t], tl[t] + tl[64 + t]);
            atomicAdd(&stats2[64 + t], tl[128 + t] + tl[192 + t]);
        }
    }
}

// ---------------- bn finalize ----------------
__global__ void fin1_kernel(const float* __restrict__ stats, const float* __restrict__ g,
                            const float* __restrict__ b, float* __restrict__ sc, float* __restrict__ sh) {
    int c = threadIdx.x;  // 128
    const float inv = 1.f / (float)(NN * MM);
    float mu = stats[c] * inv;
    float var = stats[128 + c] * inv - mu * mu;
    float s = rsqrtf(var + EPSV) * g[c];
    sc[c] = s;
    sh[c] = b[c] - mu * s;
}

__global__ void fin2_kernel(const float* __restrict__ stats2, const float* __restrict__ g,
                            const float* __restrict__ b, float* __restrict__ sc, float* __restrict__ sh) {
    int c = threadIdx.x;  // 64
    const float inv = 1.f / (float)NN;
    float mu = stats2[c] * inv;
    float var = stats2[64 + c] * inv - mu * mu;
    float s = rsqrtf(var + EPSV) * g[c];
    sc[c] = s;
    sh[c] = b[c] - mu * s;
}

// ---------------- x = softplus(x + bn2(summed)) ----------------
__global__ void update_x_kernel(float* __restrict__ x, const float* __restrict__ summed,
                                const float* __restrict__ sc2, const float* __restrict__ sh2) {
    for (int idx = blockIdx.x * blockDim.x + threadIdx.x; idx < NN * FF;
         idx += gridDim.x * blockDim.x) {
        int c = idx & 63;
        float v = x[idx] + summed[idx] * sc2[c] + sh2[c];
        x[idx] = softplusf(v);
    }
}

// ---------------- segment pooling ----------------
__global__ void seg_pool_kernel(const float* __restrict__ x, const int* __restrict__ seg,
                                float* __restrict__ csum, float* __restrict__ ccnt) {
    for (int idx = blockIdx.x * blockDim.x + threadIdx.x; idx < NN * FF;
         idx += gridDim.x * blockDim.x) {
        int i = idx >> 6;
        int c = idx & 63;
        atomicAdd(&csum[seg[i] * FF + c], x[idx]);
        if (c == 0) atomicAdd(&ccnt[seg[i]], 1.f);
    }
}

// ---------------- per-crystal head ----------------
__global__ void head_kernel(const float* __restrict__ csum, const float* __restrict__ ccnt,
                            const float* __restrict__ c2fW, const float* __restrict__ c2fb,
                            const float* __restrict__ outW, const float* __restrict__ outb,
                            float* __restrict__ out) {
    __shared__ float pl[FF];
    __shared__ float red[HH];
    int c = blockIdx.x;
    int t = threadIdx.x;
    if (t < FF) {
        float cnt = fmaxf(ccnt[c], 1.f);
        pl[t] = softplusf(csum[c * FF + t] / cnt);
    }
    __syncthreads();
    float acc = c2fb[t];
    for (int f = 0; f < FF; f++) acc += pl[f] * c2fW[f * HH + t];
    red[t] = softplusf(acc) * outW[t];
    __syncthreads();
    for (int s = 64; s > 0; s >>= 1) {
        if (t < s) red[t] += red[t + s];
        __syncthreads();
    }
    if (t == 0) out[c] = red[0] + outb[0];
}

extern "C" void kernel_launch(void* const* d_in, const int* in_sizes, int n_in,
                              void* d_out, int out_size, void* d_ws, size_t ws_size,
                              hipStream_t stream) {
    const float* atom_fea = (const float*)d_in[0];
    const float* nbr_fea  = (const float*)d_in[1];
    const int*   nbr_idx  = (const int*)d_in[2];
    const int*   seg      = (const int*)d_in[3];
    // d_in[4] = n_crystals (C hardcoded)
    const float* mask = (const float*)d_in[5];
    const float* embW = (const float*)d_in[6];
    const float* embb = (const float*)d_in[7];
    const float* fcW  = (const float*)d_in[8];
    const float* fcb  = (const float*)d_in[9];
    const float* bn1g = (const float*)d_in[10];
    const float* bn1b = (const float*)d_in[11];
    const float* bn2g = (const float*)d_in[12];
    const float* bn2b = (const float*)d_in[13];
    const float* c2fW = (const float*)d_in[14];
    const float* c2fb = (const float*)d_in[15];
    const float* outW = (const float*)d_in[16];
    const float* outb = (const float*)d_in[17];
    float* out = (float*)d_out;

    float* ws     = (float*)d_ws;
    float* x      = ws;                     // N*F
    float* summed = x + NN * FF;            // N*F
    float* Wpad   = summed + NN * FF;       // KP*G
    float* stats  = Wpad + KP * GG;         // 256 (sum | sumsq, bn1)
    float* stats2 = stats + 256;            // 128 (sum | sumsq, bn2)
    float* sc1    = stats2 + 128;           // 128
    float* sh1    = sc1 + 128;              // 128
    float* sc2    = sh1 + 128;              // 64
    float* sh2    = sc2 + 64;               // 64
    float* csum   = sh2 + 64;               // C*F
    float* ccnt   = csum + CC * FF;         // C

    embed_kernel<<<2048, 256, 0, stream>>>(atom_fea, mask, embW, embb, x);

    for (int l = 0; l < NCONV; l++) {
        hipMemsetAsync(stats, 0, (256 + 128) * sizeof(float), stream);
        padw_kernel<<<(KP * GG + 255) / 256, 256, 0, stream>>>(fcW, l, Wpad);
        conv_pass<0><<<2048, 256, 0, stream>>>(x, nbr_idx, nbr_fea, Wpad, fcb + l * GG,
                                               stats, nullptr, nullptr, nullptr, nullptr);
        fin1_kernel<<<1, 128, 0, stream>>>(stats, bn1g + l * GG, bn1b + l * GG, sc1, sh1);
        conv_pass<1><<<2048, 256, 0, stream>>>(x, nbr_idx, nbr_fea, Wpad, fcb + l * GG,
                                               nullptr, sc1, sh1, summed, stats2);
        fin2_kernel<<<1, 64, 0, stream>>>(stats2, bn2g + l * FF, bn2b + l * FF, sc2, sh2);
        update_x_kernel<<<2048, 256, 0, stream>>>(x, summed, sc2, sh2);
    }

    hipMemsetAsync(csum, 0, (CC * FF + CC) * sizeof(float), stream);
    seg_pool_kernel<<<2048, 256, 0, stream>>>(x, seg, csum, ccnt);
    head_kernel<<<CC, 128, 0, stream>>>(csum, ccnt, c2fW, c2fb, outW, outb, out);
}

// Round 2
// 3663.869 us; speedup vs baseline: 2.3176x; 2.3176x over previous
//
#include <hip/hip_runtime.h>
#include <hip/hip_bf16.h>

// CGCNN forward. R2: algebraic decomposition of the conv GEMM.
//   g[i,j,:] = y1[i,:] + y2[nbr_idx[i,j],:] + (nbr_fea @ W3)[i,j,:]
// where y1 = x@W1 + fcb, y2 = x@W2 (computed once per atom per layer).
// Two passes per layer remain (training-mode BN needs global stats of g):
//   pass A (conv_pass<0>): recompute g, accumulate per-channel sum/sumsq (bn1)
//   pass B (conv_pass<1>): recompute g, apply bn1, sigmoid*softplus, sum over M
//                          -> summed; accumulate bn2 stats
// Then update_x, segment mean-pool, head.

#define NN    100000
#define MM    12
#define ORIG  92
#define FF    64
#define NBR   41
#define HH    128
#define NCONV 3
#define CC    3125
#define K2    169      // 2F + NBR
#define KZ    41       // nbr_fea K
#define KZP   44       // KZ padded to multiple of 4
#define GG    128      // 2F
#define EPSV  1e-5f

__device__ __forceinline__ float softplusf(float v) {
    return fmaxf(v, 0.f) + log1pf(expf(-fabsf(v)));
}
__device__ __forceinline__ float sigmoidf_(float v) {
    return 1.f / (1.f + expf(-v));
}

// ---------------- embed: x = (atom_fea * mask) @ embW + embb ----------------
__global__ void embed_kernel(const float* __restrict__ af, const float* __restrict__ mask,
                             const float* __restrict__ embW, const float* __restrict__ embb,
                             float* __restrict__ x) {
    int t = threadIdx.x;
    int c = t & 63;          // feature
    int rs = t >> 6;         // 4 rows per block-iter
    float b = embb[c];
    for (int row = blockIdx.x * 4 + rs; row < NN; row += gridDim.x * 4) {
        float acc = b;
        for (int o = 0; o < ORIG; o++) {
            acc += af[row * ORIG + o] * (mask[o] * embW[o * FF + c]);
        }
        x[row * FF + c] = acc;
    }
}

// ---------------- y12: y1 = x@W1 + fcb, y2 = x@W2 (per atom) ----------------
// 256 threads, 16 atoms/block. thread: cg=t&63 -> 4 channels (of 256 = y1|y2),
// ag=t>>6 -> 4 atoms.
__launch_bounds__(256)
__global__ void y12_kernel(const float* __restrict__ x, const float* __restrict__ fcW_l,
                           const float* __restrict__ fcb_l,
                           float* __restrict__ y1, float* __restrict__ y2) {
    __shared__ float xs[16 * FF];
    int t = threadIdx.x;
    int a0 = blockIdx.x * 16;
    for (int e = t; e < 16 * FF; e += 256) xs[e] = x[a0 * FF + e];
    __syncthreads();

    int cg = t & 63;
    int ag = t >> 6;
    int c4 = cg * 4;                 // 0..255
    bool isY1 = (c4 < GG);
    const float* wbase = fcW_l + (isY1 ? c4 : (FF * GG + (c4 - GG)));

    float acc[4][4];
#pragma unroll
    for (int a = 0; a < 4; a++)
#pragma unroll
        for (int q = 0; q < 4; q++) acc[a][q] = 0.f;

    for (int k = 0; k < FF; k++) {
        float4 w = *(const float4*)&wbase[k * GG];
#pragma unroll
        for (int a = 0; a < 4; a++) {
            float xv = xs[(ag * 4 + a) * FF + k];
            acc[a][0] = fmaf(xv, w.x, acc[a][0]);
            acc[a][1] = fmaf(xv, w.y, acc[a][1]);
            acc[a][2] = fmaf(xv, w.z, acc[a][2]);
            acc[a][3] = fmaf(xv, w.w, acc[a][3]);
        }
    }

#pragma unroll
    for (int a = 0; a < 4; a++) {
        int atom = a0 + ag * 4 + a;
        if (isY1) {
            float4 o;
            o.x = acc[a][0] + fcb_l[c4 + 0];
            o.y = acc[a][1] + fcb_l[c4 + 1];
            o.z = acc[a][2] + fcb_l[c4 + 2];
            o.w = acc[a][3] + fcb_l[c4 + 3];
            *(float4*)&y1[atom * GG + c4] = o;
        } else {
            float4 o = make_float4(acc[a][0], acc[a][1], acc[a][2], acc[a][3]);
            *(float4*)&y2[atom * GG + (c4 - GG)] = o;
        }
    }
}

// ---------------- conv pass: z-GEMM (K=41) + y1/y2 add ----------------
// PASS 0: bn1 stats (sum | sumsq) -> stats[0..127 | 128..255]
// PASS 1: apply bn1, sigmoid*softplus, sum over M -> summed; bn2 stats -> stats2
template <int PASS>
__launch_bounds__(256)
__global__ void conv_pass(const float* __restrict__ y1, const float* __restrict__ y2,
                          const int* __restrict__ nidx, const float* __restrict__ nbr_fea,
                          const float* __restrict__ fcW_l,
                          float* __restrict__ stats,
                          const float* __restrict__ sc1, const float* __restrict__ sh1,
                          float* __restrict__ summed, float* __restrict__ stats2) {
    __shared__ __align__(16) float Ws[KZP * GG];      // 22.5 KB, W3 zero-padded
    __shared__ __align__(16) float tl[24 * KZP];      // 1056 floats (also scratch)
    __shared__ __align__(16) float y1s[2 * GG];
    __shared__ int nb[24];
    __shared__ float red[(PASS == 1) ? 256 : 4];
    __shared__ __align__(16) float gbuf[(PASS == 1) ? 24 * GG : 4];

    int t = threadIdx.x;
    // stage W3 once (rows 128..168 of fcW_l), pad to 44 rows
    for (int e = t; e < KZP * GG; e += 256) {
        int k = e >> 7;
        int c = e & 127;
        Ws[e] = (k < KZ) ? fcW_l[(2 * FF + k) * GG + c] : 0.f;
    }

    int cg = t & 31, c0 = cg * 4;
    int pg = t >> 5, prow = pg * 3;

    float sc[4], sh[4];
    if (PASS == 1) {
#pragma unroll
        for (int q = 0; q < 4; q++) { sc[q] = sc1[c0 + q]; sh[q] = sh1[c0 + q]; }
    }

    float sA[4] = {0, 0, 0, 0}, sB[4] = {0, 0, 0, 0};
    float s2a = 0.f, s2b = 0.f;

    const float4* Wv = (const float4*)Ws;

    for (int ab = blockIdx.x; ab < NN / 2; ab += gridDim.x) {
        int atom0 = ab * 2;
        __syncthreads();   // protect LDS from previous iteration
        if (t < 24) nb[t] = nidx[atom0 * MM + t];
        y1s[t] = y1[atom0 * GG + t];
        for (int e = t; e < 24 * KZP; e += 256) {
            int p = e / KZP;
            int k = e - p * KZP;
            tl[e] = (k < KZ) ? nbr_fea[(atom0 * MM + p) * NBR + k] : 0.f;
        }
        __syncthreads();

        float acc[3][4];
#pragma unroll
        for (int p = 0; p < 3; p++)
#pragma unroll
            for (int q = 0; q < 4; q++) acc[p][q] = 0.f;

#pragma unroll
        for (int k4 = 0; k4 < KZP / 4; k4++) {
            float4 wv4[4];
#pragma unroll
            for (int i = 0; i < 4; i++) wv4[i] = Wv[(k4 * 4 + i) * 32 + cg];
            const float* w = (const float*)wv4;
#pragma unroll
            for (int p = 0; p < 3; p++) {
                float4 tv4 = *(const float4*)&tl[(prow + p) * KZP + k4 * 4];
                float tv[4] = {tv4.x, tv4.y, tv4.z, tv4.w};
#pragma unroll
                for (int i = 0; i < 4; i++)
#pragma unroll
                    for (int q = 0; q < 4; q++)
                        acc[p][q] = fmaf(tv[i], w[i * 4 + q], acc[p][q]);
            }
        }

        // epilogue: g = z + y1[self] + y2[nbr]
#pragma unroll
        for (int p = 0; p < 3; p++) {
            int row = prow + p;
            int a1 = (row >= 12) ? 1 : 0;
            float4 yg = *(const float4*)&y2[nb[row] * GG + c0];
            float ygv[4] = {yg.x, yg.y, yg.z, yg.w};
            float g[4];
#pragma unroll
            for (int q = 0; q < 4; q++)
                g[q] = acc[p][q] + y1s[a1 * GG + c0 + q] + ygv[q];
            if (PASS == 0) {
#pragma unroll
                for (int q = 0; q < 4; q++) { sA[q] += g[q]; sB[q] += g[q] * g[q]; }
            } else {
#pragma unroll
                for (int q = 0; q < 4; q++)
                    gbuf[row * GG + c0 + q] = g[q] * sc[q] + sh[q];
            }
        }

        if (PASS == 1) {
            __syncthreads();
            // all 256 threads: aslot = t>>7, half = (t>>6)&1, c = t&63
            int aslot = t >> 7, half = (t >> 6) & 1, c = t & 63;
            float s = 0.f;
#pragma unroll
            for (int j = half * 6; j < half * 6 + 6; j++) {
                float fv = gbuf[(aslot * 12 + j) * GG + c];
                float cv = gbuf[(aslot * 12 + j) * GG + FF + c];
                s += sigmoidf_(fv) * softplusf(cv);
            }
            red[t] = s;
            __syncthreads();
            if (t < 128) {
                int as2 = t >> 6, c2 = t & 63;
                float sm = red[as2 * 128 + c2] + red[as2 * 128 + 64 + c2];
                summed[(atom0 + as2) * FF + c2] = sm;
                s2a += sm;
                s2b += sm * sm;
            }
        }
    }

    // ------- end-of-kernel block reductions (tl reused as scratch) -------
    if (PASS == 0) {
        __syncthreads();
#pragma unroll
        for (int q = 0; q < 4; q++) tl[t * 4 + q] = sA[q];
        __syncthreads();
        if (t < 32) {
#pragma unroll
            for (int q = 0; q < 4; q++) {
                float s = 0.f;
                for (int g2 = 0; g2 < 8; g2++) s += tl[(g2 * 32 + t) * 4 + q];
                atomicAdd(&stats[t * 4 + q], s);
            }
        }
        __syncthreads();
#pragma unroll
        for (int q = 0; q < 4; q++) tl[t * 4 + q] = sB[q];
        __syncthreads();
        if (t < 32) {
#pragma unroll
            for (int q = 0; q < 4; q++) {
                float s = 0.f;
                for (int g2 = 0; g2 < 8; g2++) s += tl[(g2 * 32 + t) * 4 + q];
                atomicAdd(&stats[128 + t * 4 + q], s);
            }
        }
    } else {
        __syncthreads();
        if (t < 128) { tl[t] = s2a; tl[128 + t] = s2b; }
        __syncthreads();
        if (t < 64) {
            atomicAdd(&stats2[t], tl[t] + tl[64 + t]);
            atomicAdd(&stats2[64 + t], tl[128 + t] + tl[192 + t]);
        }
    }
}

// ---------------- bn finalize ----------------
__global__ void fin1_kernel(const float* __restrict__ stats, const float* __restrict__ g,
                            const float* __restrict__ b, float* __restrict__ sc, float* __restrict__ sh) {
    int c = threadIdx.x;  // 128
    const float inv = 1.f / (float)(NN * MM);
    float mu = stats[c] * inv;
    float var = stats[128 + c] * inv - mu * mu;
    float s = rsqrtf(var + EPSV) * g[c];
    sc[c] = s;
    sh[c] = b[c] - mu * s;
}

__global__ void fin2_kernel(const float* __restrict__ stats2, const float* __restrict__ g,
                            const float* __restrict__ b, float* __restrict__ sc, float* __restrict__ sh) {
    int c = threadIdx.x;  // 64
    const float inv = 1.f / (float)NN;
    float mu = stats2[c] * inv;
    float var = stats2[64 + c] * inv - mu * mu;
    float s = rsqrtf(var + EPSV) * g[c];
    sc[c] = s;
    sh[c] = b[c] - mu * s;
}

// ---------------- x = softplus(x + bn2(summed)) ----------------
__global__ void update_x_kernel(float* __restrict__ x, const float* __restrict__ summed,
                                const float* __restrict__ sc2, const float* __restrict__ sh2) {
    for (int idx = blockIdx.x * blockDim.x + threadIdx.x; idx < NN * FF;
         idx += gridDim.x * blockDim.x) {
        int c = idx & 63;
        float v = x[idx] + summed[idx] * sc2[c] + sh2[c];
        x[idx] = softplusf(v);
    }
}

// ---------------- segment pooling ----------------
__global__ void seg_pool_kernel(const float* __restrict__ x, const int* __restrict__ seg,
                                float* __restrict__ csum, float* __restrict__ ccnt) {
    for (int idx = blockIdx.x * blockDim.x + threadIdx.x; idx < NN * FF;
         idx += gridDim.x * blockDim.x) {
        int i = idx >> 6;
        int c = idx & 63;
        atomicAdd(&csum[seg[i] * FF + c], x[idx]);
        if (c == 0) atomicAdd(&ccnt[seg[i]], 1.f);
    }
}

// ---------------- per-crystal head ----------------
__global__ void head_kernel(const float* __restrict__ csum, const float* __restrict__ ccnt,
                            const float* __restrict__ c2fW, const float* __restrict__ c2fb,
                            const float* __restrict__ outW, const float* __restrict__ outb,
                            float* __restrict__ out) {
    __shared__ float pl[FF];
    __shared__ float red[HH];
    int c = blockIdx.x;
    int t = threadIdx.x;
    if (t < FF) {
        float cnt = fmaxf(ccnt[c], 1.f);
        pl[t] = softplusf(csum[c * FF + t] / cnt);
    }
    __syncthreads();
    float acc = c2fb[t];
    for (int f = 0; f < FF; f++) acc += pl[f] * c2fW[f * HH + t];
    red[t] = softplusf(acc) * outW[t];
    __syncthreads();
    for (int s = 64; s > 0; s >>= 1) {
        if (t < s) red[t] += red[t + s];
        __syncthreads();
    }
    if (t == 0) out[c] = red[0] + outb[0];
}

extern "C" void kernel_launch(void* const* d_in, const int* in_sizes, int n_in,
                              void* d_out, int out_size, void* d_ws, size_t ws_size,
                              hipStream_t stream) {
    const float* atom_fea = (const float*)d_in[0];
    const float* nbr_fea  = (const float*)d_in[1];
    const int*   nbr_idx  = (const int*)d_in[2];
    const int*   seg      = (const int*)d_in[3];
    const float* mask = (const float*)d_in[5];
    const float* embW = (const float*)d_in[6];
    const float* embb = (const float*)d_in[7];
    const float* fcW  = (const float*)d_in[8];
    const float* fcb  = (const float*)d_in[9];
    const float* bn1g = (const float*)d_in[10];
    const float* bn1b = (const float*)d_in[11];
    const float* bn2g = (const float*)d_in[12];
    const float* bn2b = (const float*)d_in[13];
    const float* c2fW = (const float*)d_in[14];
    const float* c2fb = (const float*)d_in[15];
    const float* outW = (const float*)d_in[16];
    const float* outb = (const float*)d_in[17];
    float* out = (float*)d_out;

    float* ws     = (float*)d_ws;
    float* x      = ws;                     // N*F
    float* summed = x + NN * FF;            // N*F
    float* y1     = summed + NN * FF;       // N*G
    float* y2     = y1 + NN * GG;           // N*G
    float* stats  = y2 + NN * GG;           // 256
    float* stats2 = stats + 256;            // 128
    float* sc1    = stats2 + 128;           // 128
    float* sh1    = sc1 + 128;              // 128
    float* sc2    = sh1 + 128;              // 64
    float* sh2    = sc2 + 64;               // 64
    float* csum   = sh2 + 64;               // C*F
    float* ccnt   = csum + CC * FF;         // C

    embed_kernel<<<2048, 256, 0, stream>>>(atom_fea, mask, embW, embb, x);

    for (int l = 0; l < NCONV; l++) {
        const float* fcW_l = fcW + l * K2 * GG;
        hipMemsetAsync(stats, 0, (256 + 128) * sizeof(float), stream);
        y12_kernel<<<NN / 16, 256, 0, stream>>>(x, fcW_l, fcb + l * GG, y1, y2);
        conv_pass<0><<<2048, 256, 0, stream>>>(y1, y2, nbr_idx, nbr_fea, fcW_l,
                                               stats, nullptr, nullptr, nullptr, nullptr);
        fin1_kernel<<<1, 128, 0, stream>>>(stats, bn1g + l * GG, bn1b + l * GG, sc1, sh1);
        conv_pass<1><<<2048, 256, 0, stream>>>(y1, y2, nbr_idx, nbr_fea, fcW_l,
                                               nullptr, sc1, sh1, summed, stats2);
        fin2_kernel<<<1, 64, 0, stream>>>(stats2, bn2g + l * FF, bn2b + l * FF, sc2, sh2);
        update_x_kernel<<<2048, 256, 0, stream>>>(x, summed, sc2, sh2);
    }

    hipMemsetAsync(csum, 0, (CC * FF + CC) * sizeof(float), stream);
    seg_pool_kernel<<<2048, 256, 0, stream>>>(x, seg, csum, ccnt);
    head_kernel<<<CC, 128, 0, stream>>>(csum, ccnt, c2fW, c2fb, outW, outb, out);
}

// Round 4
// 2895.610 us; speedup vs baseline: 2.9325x; 1.2653x over previous
//
#include <hip/hip_runtime.h>
#include <hip/hip_bf16.h>

// CGCNN forward. R4 = R3 (MFMA bf16 conv GEMM) + ccnt memset fix.
// R3 bug: ccnt was moved away from csum but the single memset assumed
// adjacency -> ccnt tail accumulated across graph replays (tripwire).
// ccnt is now adjacent to csum again; one memset covers both fully.

#define NN    100000
#define MM    12
#define ORIG  92
#define FF    64
#define NBR   41
#define HH    128
#define NCONV 3
#define CC    3125
#define K2    169
#define GG    128
#define EPSV  1e-5f

#define TILE_ATOMS 8
#define TILE_ROWS  96            // 8 atoms * 12 edges
#define NTILES     (NN / TILE_ATOMS)   // 12500 exactly
#define SLOTS      24            // 24 * 16B = 384B = 192 bf16 per A row
#define WPK_L      (48 * 64 * 8) // ushorts per layer of packed W

typedef __attribute__((ext_vector_type(8))) short bf16x8;
typedef __attribute__((ext_vector_type(4))) float f32x4;

__device__ __forceinline__ float softplusf(float v) {
    return fmaxf(v, 0.f) + log1pf(expf(-fabsf(v)));
}
__device__ __forceinline__ float sigmoidf_(float v) {
    return 1.f / (1.f + expf(-v));
}
__device__ __forceinline__ ushort f2bf(float f) {
    __hip_bfloat16 h = __float2bfloat16(f);
    return *(ushort*)&h;
}

// ---------------- embed: x = (atom_fea * mask) @ embW + embb ; also xb (bf16) ----------------
__global__ void embed_kernel(const float* __restrict__ af, const float* __restrict__ mask,
                             const float* __restrict__ embW, const float* __restrict__ embb,
                             float* __restrict__ x, ushort* __restrict__ xb) {
    int t = threadIdx.x;
    int c = t & 63;
    int rs = t >> 6;
    float b = embb[c];
    for (int row = blockIdx.x * 4 + rs; row < NN; row += gridDim.x * 4) {
        float acc = b;
        for (int o = 0; o < ORIG; o++) {
            acc += af[row * ORIG + o] * (mask[o] * embW[o * FF + c]);
        }
        x[row * FF + c] = acc;
        xb[row * FF + c] = f2bf(acc);
    }
}

// ---------------- pack W into MFMA B-fragment order ----------------
// wpk[((l*48 + cf*6 + kk)*64 + lane)*8 + i] = bf16(W_l[kk*32 + (lane>>4)*8 + i][cf*16 + (lane&15)])
__global__ void packW_kernel(const float* __restrict__ fcW, ushort* __restrict__ wpk) {
    int b = blockIdx.x;            // 0..143 = l*48 + cf*6 + kk
    int l = b / 48;
    int r = b - l * 48;
    int cf = r / 6;
    int kk = r - cf * 6;
    int lane = threadIdx.x;        // 0..63
    int c = cf * 16 + (lane & 15);
#pragma unroll
    for (int i = 0; i < 8; i++) {
        int k = kk * 32 + (lane >> 4) * 8 + i;
        float v = (k < K2) ? fcW[(l * K2 + k) * GG + c] : 0.f;
        wpk[((size_t)b * 64 + lane) * 8 + i] = f2bf(v);
    }
}

// ---------------- conv pass (MFMA) ----------------
template <int PASS>
__launch_bounds__(256, 2)
__global__ void conv_mfma(const ushort* __restrict__ xb, const float* __restrict__ nbr_fea,
                          const int* __restrict__ nidx, const ushort* __restrict__ wpk_l,
                          const float* __restrict__ fcb_l,
                          float* __restrict__ stats,
                          const float* __restrict__ sc1, const float* __restrict__ sh1,
                          float* __restrict__ summed, float* __restrict__ stats2) {
    __shared__ __align__(16) ushort As[TILE_ROWS * 192];   // 36 KB, swizzled
    __shared__ int nb[TILE_ROWS];
    __shared__ float gacc[TILE_ATOMS * FF];                // 2 KB (PASS1)
    __shared__ float red[256];

    const int t = threadIdx.x;
    const int lane = t & 63;
    const int w = t >> 6;          // wave 0..3
    const int l15 = lane & 15;
    const int lg = lane >> 4;      // 0..3

    // B fragments: cf = w (filt cols) and w+4 (core cols), kk = 0..5
    bf16x8 bfrag[2][6];
#pragma unroll
    for (int c2 = 0; c2 < 2; c2++)
#pragma unroll
        for (int kk = 0; kk < 6; kk++)
            bfrag[c2][kk] = *(const bf16x8*)&wpk_l[((((w + 4 * c2) * 6 + kk) * 64 + lane) * 8)];

    const int chF = w * 16 + l15;      // 0..63
    const int chC = chF + 64;          // 64..127
    const float bF = fcb_l[chF], bC = fcb_l[chC];
    float scF = 0.f, shF = 0.f, scC = 0.f, shC = 0.f;
    if (PASS == 1) { scF = sc1[chF]; shF = sh1[chF]; scC = sc1[chC]; shC = sh1[chC]; }

    float sAF = 0.f, sBF = 0.f, sAC = 0.f, sBC = 0.f;  // PASS0 stats partials
    float s2a = 0.f, s2b = 0.f;                         // PASS1 bn2 partials (channel t&63)

    for (int tile = blockIdx.x; tile < NTILES; tile += gridDim.x) {
        const int ebase = tile * TILE_ROWS;
        __syncthreads();   // protect LDS from previous tile
        if (t < TILE_ROWS) nb[t] = nidx[ebase + t];
        if (PASS == 1) { gacc[t] = 0.f; gacc[256 + t] = 0.f; }
        __syncthreads();

        // stage A: row r holds [xb[self] (64) | xb[nbr] (64) | bf16(nbr_fea) pad64]
#pragma unroll
        for (int e = t; e < TILE_ROWS * SLOTS; e += 256) {  // 9 iters
            int row = e / SLOTS;
            int slot = e - row * SLOTS;
            uint4 val;
            if (slot < 16) {
                int a = (slot < 8) ? (tile * TILE_ATOMS + row / 12) : nb[row];
                val = *(const uint4*)&xb[a * 64 + (slot & 7) * 8];
            } else {
                int kb = (slot - 16) * 8;
                const float* src = nbr_fea + (size_t)(ebase + row) * NBR + kb;
                ushort h[8];
#pragma unroll
                for (int i = 0; i < 8; i++)
                    h[i] = (kb + i < NBR) ? f2bf(src[i]) : (ushort)0;
                val.x = (uint)h[0] | ((uint)h[1] << 16);
                val.y = (uint)h[2] | ((uint)h[3] << 16);
                val.z = (uint)h[4] | ((uint)h[5] << 16);
                val.w = (uint)h[6] | ((uint)h[7] << 16);
            }
            *(uint4*)&As[row * 192 + ((slot ^ (row & 7)) * 8)] = val;
        }
        __syncthreads();

        // MFMA: 6 row-frags x {filt,core} col-frags x 6 K-chunks
        f32x4 acc[6][2];
#pragma unroll
        for (int rf = 0; rf < 6; rf++)
#pragma unroll
            for (int c2 = 0; c2 < 2; c2++) acc[rf][c2] = (f32x4){0.f, 0.f, 0.f, 0.f};

#pragma unroll
        for (int kk = 0; kk < 6; kk++) {
#pragma unroll
            for (int rf = 0; rf < 6; rf++) {
                int row = rf * 16 + l15;
                int slot = kk * 4 + lg;
                bf16x8 a = *(const bf16x8*)&As[row * 192 + ((slot ^ (row & 7)) * 8)];
                acc[rf][0] = __builtin_amdgcn_mfma_f32_16x16x32_bf16(a, bfrag[0][kk], acc[rf][0], 0, 0, 0);
                acc[rf][1] = __builtin_amdgcn_mfma_f32_16x16x32_bf16(a, bfrag[1][kk], acc[rf][1], 0, 0, 0);
            }
        }

        // epilogue. D layout: edge-row = rf*16 + lg*4 + q, channel = cf*16 + l15
        if (PASS == 0) {
#pragma unroll
            for (int rf = 0; rf < 6; rf++)
#pragma unroll
                for (int q = 0; q < 4; q++) {
                    float gF = acc[rf][0][q] + bF;
                    float gC = acc[rf][1][q] + bC;
                    sAF += gF; sBF += gF * gF;
                    sAC += gC; sBC += gC * gC;
                }
        } else {
#pragma unroll
            for (int rf = 0; rf < 6; rf++) {
                int r0 = rf * 16 + lg * 4;         // 4 rows r0..r0+3, all in atom r0/12
                float p = 0.f;
#pragma unroll
                for (int q = 0; q < 4; q++) {
                    float gF = (acc[rf][0][q] + bF) * scF + shF;
                    float gC = (acc[rf][1][q] + bC) * scC + shC;
                    p += sigmoidf_(gF) * softplusf(gC);
                }
                atomicAdd(&gacc[(r0 / 12) * FF + chF], p);
            }
            __syncthreads();
#pragma unroll
            for (int rep = 0; rep < 2; rep++) {
                int idx = rep * 256 + t;
                int a = idx >> 6, c = idx & 63;    // c == t&63 for both reps
                float sm = gacc[idx];
                summed[(tile * TILE_ATOMS + a) * FF + c] = sm;
                s2a += sm; s2b += sm * sm;
            }
        }
    }

    // ------- end-of-kernel block reductions -------
    // channel c holder threads: t = (c>>4)*64 + lg*16 + (c&15), lg=0..3
    if (PASS == 0) {
        __syncthreads(); red[t] = sAF; __syncthreads();
        if (t < 64) {
            float s = 0.f;
#pragma unroll
            for (int g2 = 0; g2 < 4; g2++) s += red[(t >> 4) * 64 + g2 * 16 + (t & 15)];
            atomicAdd(&stats[t], s);
        }
        __syncthreads(); red[t] = sBF; __syncthreads();
        if (t < 64) {
            float s = 0.f;
#pragma unroll
            for (int g2 = 0; g2 < 4; g2++) s += red[(t >> 4) * 64 + g2 * 16 + (t & 15)];
            atomicAdd(&stats[128 + t], s);
        }
        __syncthreads(); red[t] = sAC; __syncthreads();
        if (t < 64) {
            float s = 0.f;
#pragma unroll
            for (int g2 = 0; g2 < 4; g2++) s += red[(t >> 4) * 64 + g2 * 16 + (t & 15)];
            atomicAdd(&stats[64 + t], s);
        }
        __syncthreads(); red[t] = sBC; __syncthreads();
        if (t < 64) {
            float s = 0.f;
#pragma unroll
            for (int g2 = 0; g2 < 4; g2++) s += red[(t >> 4) * 64 + g2 * 16 + (t & 15)];
            atomicAdd(&stats[192 + t], s);
        }
    } else {
        __syncthreads(); red[t] = s2a; __syncthreads();
        if (t < 64) {
            float s = red[t] + red[64 + t] + red[128 + t] + red[192 + t];
            atomicAdd(&stats2[t], s);
        }
        __syncthreads(); red[t] = s2b; __syncthreads();
        if (t < 64) {
            float s = red[t] + red[64 + t] + red[128 + t] + red[192 + t];
            atomicAdd(&stats2[64 + t], s);
        }
    }
}

// ---------------- bn finalize ----------------
__global__ void fin1_kernel(const float* __restrict__ stats, const float* __restrict__ g,
                            const float* __restrict__ b, float* __restrict__ sc, float* __restrict__ sh) {
    int c = threadIdx.x;  // 128
    const float inv = 1.f / (float)(NN * MM);
    float mu = stats[c] * inv;
    float var = stats[128 + c] * inv - mu * mu;
    float s = rsqrtf(var + EPSV) * g[c];
    sc[c] = s;
    sh[c] = b[c] - mu * s;
}

__global__ void fin2_kernel(const float* __restrict__ stats2, const float* __restrict__ g,
                            const float* __restrict__ b, float* __restrict__ sc, float* __restrict__ sh) {
    int c = threadIdx.x;  // 64
    const float inv = 1.f / (float)NN;
    float mu = stats2[c] * inv;
    float var = stats2[64 + c] * inv - mu * mu;
    float s = rsqrtf(var + EPSV) * g[c];
    sc[c] = s;
    sh[c] = b[c] - mu * s;
}

// ---------------- x = softplus(x + bn2(summed)) ; refresh xb ----------------
__global__ void update_x_kernel(float* __restrict__ x, ushort* __restrict__ xb,
                                const float* __restrict__ summed,
                                const float* __restrict__ sc2, const float* __restrict__ sh2) {
    for (int idx = blockIdx.x * blockDim.x + threadIdx.x; idx < NN * FF;
         idx += gridDim.x * blockDim.x) {
        int c = idx & 63;
        float v = softplusf(x[idx] + summed[idx] * sc2[c] + sh2[c]);
        x[idx] = v;
        xb[idx] = f2bf(v);
    }
}

// ---------------- segment pooling ----------------
__global__ void seg_pool_kernel(const float* __restrict__ x, const int* __restrict__ seg,
                                float* __restrict__ csum, float* __restrict__ ccnt) {
    for (int idx = blockIdx.x * blockDim.x + threadIdx.x; idx < NN * FF;
         idx += gridDim.x * blockDim.x) {
        int i = idx >> 6;
        int c = idx & 63;
        atomicAdd(&csum[seg[i] * FF + c], x[idx]);
        if (c == 0) atomicAdd(&ccnt[seg[i]], 1.f);
    }
}

// ---------------- per-crystal head ----------------
__global__ void head_kernel(const float* __restrict__ csum, const float* __restrict__ ccnt,
                            const float* __restrict__ c2fW, const float* __restrict__ c2fb,
                            const float* __restrict__ outW, const float* __restrict__ outb,
                            float* __restrict__ out) {
    __shared__ float pl[FF];
    __shared__ float red[HH];
    int c = blockIdx.x;
    int t = threadIdx.x;
    if (t < FF) {
        float cnt = fmaxf(ccnt[c], 1.f);
        pl[t] = softplusf(csum[c * FF + t] / cnt);
    }
    __syncthreads();
    float acc = c2fb[t];
    for (int f = 0; f < FF; f++) acc += pl[f] * c2fW[f * HH + t];
    red[t] = softplusf(acc) * outW[t];
    __syncthreads();
    for (int s = 64; s > 0; s >>= 1) {
        if (t < s) red[t] += red[t + s];
        __syncthreads();
    }
    if (t == 0) out[c] = red[0] + outb[0];
}

extern "C" void kernel_launch(void* const* d_in, const int* in_sizes, int n_in,
                              void* d_out, int out_size, void* d_ws, size_t ws_size,
                              hipStream_t stream) {
    const float* atom_fea = (const float*)d_in[0];
    const float* nbr_fea  = (const float*)d_in[1];
    const int*   nbr_idx  = (const int*)d_in[2];
    const int*   seg      = (const int*)d_in[3];
    const float* mask = (const float*)d_in[5];
    const float* embW = (const float*)d_in[6];
    const float* embb = (const float*)d_in[7];
    const float* fcW  = (const float*)d_in[8];
    const float* fcb  = (const float*)d_in[9];
    const float* bn1g = (const float*)d_in[10];
    const float* bn1b = (const float*)d_in[11];
    const float* bn2g = (const float*)d_in[12];
    const float* bn2b = (const float*)d_in[13];
    const float* c2fW = (const float*)d_in[14];
    const float* c2fb = (const float*)d_in[15];
    const float* outW = (const float*)d_in[16];
    const float* outb = (const float*)d_in[17];
    float* out = (float*)d_out;

    // ws layout (f32 region, then ushort region; all 16B aligned)
    // NOTE: ccnt MUST stay adjacent to csum — one memset covers both each call.
    float* ws     = (float*)d_ws;
    float* x      = ws;                       // N*F
    float* summed = x + NN * FF;              // N*F
    float* csum   = summed + NN * FF;         // CC*FF
    float* ccnt   = csum + CC * FF;           // CC (+3 pad -> 3128)
    float* stats  = ccnt + 3128;              // 256 (bn1 sum|sumsq)
    float* stats2 = stats + 256;              // 128 (bn2 sum|sumsq)
    float* sc1    = stats2 + 128;             // 128
    float* sh1    = sc1 + 128;                // 128
    float* sc2    = sh1 + 128;                // 64
    float* sh2    = sc2 + 64;                 // 64
    ushort* xb    = (ushort*)(sh2 + 64);      // N*F bf16
    ushort* wpk   = xb + NN * FF;             // 3 * WPK_L bf16

    packW_kernel<<<144, 64, 0, stream>>>(fcW, wpk);
    embed_kernel<<<2048, 256, 0, stream>>>(atom_fea, mask, embW, embb, x, xb);

    for (int l = 0; l < NCONV; l++) {
        const ushort* wpk_l = wpk + l * WPK_L;
        hipMemsetAsync(stats, 0, (256 + 128) * sizeof(float), stream);
        conv_mfma<0><<<2048, 256, 0, stream>>>(xb, nbr_fea, nbr_idx, wpk_l, fcb + l * GG,
                                               stats, nullptr, nullptr, nullptr, nullptr);
        fin1_kernel<<<1, 128, 0, stream>>>(stats, bn1g + l * GG, bn1b + l * GG, sc1, sh1);
        conv_mfma<1><<<2048, 256, 0, stream>>>(xb, nbr_fea, nbr_idx, wpk_l, fcb + l * GG,
                                               nullptr, sc1, sh1, summed, stats2);
        fin2_kernel<<<1, 64, 0, stream>>>(stats2, bn2g + l * FF, bn2b + l * FF, sc2, sh2);
        update_x_kernel<<<2048, 256, 0, stream>>>(x, xb, summed, sc2, sh2);
    }

    hipMemsetAsync(csum, 0, (CC * FF + CC) * sizeof(float), stream);
    seg_pool_kernel<<<2048, 256, 0, stream>>>(x, seg, csum, ccnt);
    head_kernel<<<CC, 128, 0, stream>>>(csum, ccnt, c2fW, c2fb, outW, outb, out);
}

// Round 5
// 2209.609 us; speedup vs baseline: 3.8429x; 1.3105x over previous
//
#include <hip/hip_runtime.h>
#include <hip/hip_bf16.h>

// CGCNN forward. R5: single-GEMM-per-layer with stored bf16 g.
//   conv_g: g = [xb_self | xb_nbr | nbrb] @ W + fcb (MFMA bf16, K=192),
//           round g->bf16, store to global, bn1 stats on the ROUNDED values.
//   gated:  stream g, apply bn1, sigmoid(filt)*softplus(core), sum over M
//           -> summed; bn2 stats.
// nbr_fea is pre-converted once to bf16 padded-64 (nbrb) so conv staging is
// pure uint4 copies. Runtime ws_size check: if ws < ~526MB, fall back to the
// R4 two-pass recompute path (identical results/behavior to R4).

#define NN    100000
#define MM    12
#define ORIG  92
#define FF    64
#define NBR   41
#define HH    128
#define NCONV 3
#define CC    3125
#define K2    169
#define GG    128
#define EPSV  1e-5f

#define TILE_ATOMS 8
#define TILE_ROWS  96                  // 8 atoms * 12 edges
#define NTILES     (NN / TILE_ATOMS)   // 12500
#define SLOTS      24                  // 24 * 16B = 384B = 192 bf16 per A row
#define WPK_L      (48 * 64 * 8)       // ushorts per layer of packed W

typedef __attribute__((ext_vector_type(8))) short bf16x8;
typedef __attribute__((ext_vector_type(4))) float f32x4;

__device__ __forceinline__ float softplusf(float v) {
    return fmaxf(v, 0.f) + log1pf(expf(-fabsf(v)));
}
__device__ __forceinline__ float sigmoidf_(float v) {
    return 1.f / (1.f + expf(-v));
}
__device__ __forceinline__ ushort f2bf(float f) {
    __hip_bfloat16 h = __float2bfloat16(f);
    return *(ushort*)&h;
}
__device__ __forceinline__ float bf2f(ushort h) {
    uint u = ((uint)h) << 16;
    return __uint_as_float(u);
}

// ---------------- embed: x = (atom_fea * mask) @ embW + embb ; also xb ----------------
__global__ void embed_kernel(const float* __restrict__ af, const float* __restrict__ mask,
                             const float* __restrict__ embW, const float* __restrict__ embb,
                             float* __restrict__ x, ushort* __restrict__ xb) {
    int t = threadIdx.x;
    int c = t & 63;
    int rs = t >> 6;
    float b = embb[c];
    for (int row = blockIdx.x * 4 + rs; row < NN; row += gridDim.x * 4) {
        float acc = b;
        for (int o = 0; o < ORIG; o++) {
            acc += af[row * ORIG + o] * (mask[o] * embW[o * FF + c]);
        }
        x[row * FF + c] = acc;
        xb[row * FF + c] = f2bf(acc);
    }
}

// ---------------- pack W into MFMA B-fragment order ----------------
__global__ void packW_kernel(const float* __restrict__ fcW, ushort* __restrict__ wpk) {
    int b = blockIdx.x;            // 0..143 = l*48 + cf*6 + kk
    int l = b / 48;
    int r = b - l * 48;
    int cf = r / 6;
    int kk = r - cf * 6;
    int lane = threadIdx.x;        // 0..63
    int c = cf * 16 + (lane & 15);
#pragma unroll
    for (int i = 0; i < 8; i++) {
        int k = kk * 32 + (lane >> 4) * 8 + i;
        float v = (k < K2) ? fcW[(l * K2 + k) * GG + c] : 0.f;
        wpk[((size_t)b * 64 + lane) * 8 + i] = f2bf(v);
    }
}

// ---------------- prepack nbr_fea -> bf16 padded to 64 ----------------
__global__ void prepack_nbr(const float* __restrict__ nbr_fea, ushort* __restrict__ nbrb) {
    const size_t total = (size_t)NN * MM * 8;   // uint4 units
    for (size_t u = (size_t)blockIdx.x * blockDim.x + threadIdx.x; u < total;
         u += (size_t)gridDim.x * blockDim.x) {
        size_t row = u >> 3;
        int u4 = (int)(u & 7);
        int kb = u4 * 8;
        const float* src = nbr_fea + row * NBR + kb;
        ushort h[8];
#pragma unroll
        for (int i = 0; i < 8; i++)
            h[i] = (kb + i < NBR) ? f2bf(src[i]) : (ushort)0;
        uint4 val;
        val.x = (uint)h[0] | ((uint)h[1] << 16);
        val.y = (uint)h[2] | ((uint)h[3] << 16);
        val.z = (uint)h[4] | ((uint)h[5] << 16);
        val.w = (uint)h[6] | ((uint)h[7] << 16);
        ((uint4*)nbrb)[u] = val;
    }
}

// ---------------- conv_g: MFMA GEMM + g store + bn1 stats ----------------
__launch_bounds__(256, 4)
__global__ void conv_g(const ushort* __restrict__ xb, const ushort* __restrict__ nbrb,
                       const int* __restrict__ nidx, const ushort* __restrict__ wpk_l,
                       const float* __restrict__ fcb_l,
                       float* __restrict__ stats, ushort* __restrict__ g) {
    __shared__ __align__(16) ushort As[TILE_ROWS * 192];   // 36.9 KB (also gb repack)
    __shared__ int nb[TILE_ROWS];
    __shared__ float red[256];
    ushort* gb = As;   // reused after MFMA (barrier-protected)

    const int t = threadIdx.x;
    const int lane = t & 63;
    const int w = t >> 6;
    const int l15 = lane & 15;
    const int lg = lane >> 4;

    bf16x8 bfrag[2][6];
#pragma unroll
    for (int c2 = 0; c2 < 2; c2++)
#pragma unroll
        for (int kk = 0; kk < 6; kk++)
            bfrag[c2][kk] = *(const bf16x8*)&wpk_l[((((w + 4 * c2) * 6 + kk) * 64 + lane) * 8)];

    const int chF = w * 16 + l15;
    const int chC = chF + 64;
    const float bF = fcb_l[chF], bC = fcb_l[chC];

    float sAF = 0.f, sBF = 0.f, sAC = 0.f, sBC = 0.f;

    for (int tile = blockIdx.x; tile < NTILES; tile += gridDim.x) {
        const int ebase = tile * TILE_ROWS;
        __syncthreads();   // protect LDS (As/gb, nb) from previous tile
        if (t < TILE_ROWS) nb[t] = nidx[ebase + t];
        __syncthreads();

        // stage A: all uint4 copies
#pragma unroll
        for (int e = t; e < TILE_ROWS * SLOTS; e += 256) {  // 9 iters exact
            int row = e / SLOTS;
            int slot = e - row * SLOTS;
            const uint4* src;
            if (slot < 8)
                src = (const uint4*)&xb[(tile * TILE_ATOMS + row / 12) * 64 + slot * 8];
            else if (slot < 16)
                src = (const uint4*)&xb[nb[row] * 64 + (slot - 8) * 8];
            else
                src = (const uint4*)&nbrb[(size_t)(ebase + row) * 64 + (slot - 16) * 8];
            *(uint4*)&As[row * 192 + ((slot ^ (row & 7)) * 8)] = *src;
        }
        __syncthreads();

        f32x4 acc[6][2];
#pragma unroll
        for (int rf = 0; rf < 6; rf++)
#pragma unroll
            for (int c2 = 0; c2 < 2; c2++) acc[rf][c2] = (f32x4){0.f, 0.f, 0.f, 0.f};

#pragma unroll
        for (int kk = 0; kk < 6; kk++) {
#pragma unroll
            for (int rf = 0; rf < 6; rf++) {
                int row = rf * 16 + l15;
                int slot = kk * 4 + lg;
                bf16x8 a = *(const bf16x8*)&As[row * 192 + ((slot ^ (row & 7)) * 8)];
                acc[rf][0] = __builtin_amdgcn_mfma_f32_16x16x32_bf16(a, bfrag[0][kk], acc[rf][0], 0, 0, 0);
                acc[rf][1] = __builtin_amdgcn_mfma_f32_16x16x32_bf16(a, bfrag[1][kk], acc[rf][1], 0, 0, 0);
            }
        }
        __syncthreads();   // all A-frag reads done before gb overwrite

        // epilogue: round to bf16, stats on rounded values, swizzled LDS write
#pragma unroll
        for (int rf = 0; rf < 6; rf++)
#pragma unroll
            for (int q = 0; q < 4; q++) {
                int row = rf * 16 + lg * 4 + q;
                int swz = ((row >> 2) & 3) << 4;
                ushort hF = f2bf(acc[rf][0][q] + bF);
                ushort hC = f2bf(acc[rf][1][q] + bC);
                float gF = bf2f(hF), gC = bf2f(hC);
                sAF += gF; sBF += gF * gF;
                sAC += gC; sBC += gC * gC;
                gb[row * GG + (chF ^ swz)] = hF;
                gb[row * GG + (chC ^ swz)] = hC;
            }
        __syncthreads();

        // copy gb -> g (coalesced uint4)
        const uint4* gbu = (const uint4*)gb;
#pragma unroll
        for (int i = 0; i < 6; i++) {   // 1536 uint4 = 6*256
            int idx = i * 256 + t;
            int row = idx >> 4;
            int c8 = idx & 15;
            uint4 v = gbu[row * 16 + (c8 ^ (((row >> 2) & 3) << 1))];
            *(uint4*)&g[((size_t)(ebase + row)) * GG + c8 * 8] = v;
        }
    }

    // ------- end-of-kernel stats reduction -------
    // channel c holder threads: t = (c>>4)*64 + lg*16 + (c&15)
    __syncthreads(); red[t] = sAF; __syncthreads();
    if (t < 64) {
        float s = 0.f;
#pragma unroll
        for (int g2 = 0; g2 < 4; g2++) s += red[(t >> 4) * 64 + g2 * 16 + (t & 15)];
        atomicAdd(&stats[t], s);
    }
    __syncthreads(); red[t] = sBF; __syncthreads();
    if (t < 64) {
        float s = 0.f;
#pragma unroll
        for (int g2 = 0; g2 < 4; g2++) s += red[(t >> 4) * 64 + g2 * 16 + (t & 15)];
        atomicAdd(&stats[128 + t], s);
    }
    __syncthreads(); red[t] = sAC; __syncthreads();
    if (t < 64) {
        float s = 0.f;
#pragma unroll
        for (int g2 = 0; g2 < 4; g2++) s += red[(t >> 4) * 64 + g2 * 16 + (t & 15)];
        atomicAdd(&stats[64 + t], s);
    }
    __syncthreads(); red[t] = sBC; __syncthreads();
    if (t < 64) {
        float s = 0.f;
#pragma unroll
        for (int g2 = 0; g2 < 4; g2++) s += red[(t >> 4) * 64 + g2 * 16 + (t & 15)];
        atomicAdd(&stats[192 + t], s);
    }
}

// ---------------- gated: stream g, bn1 apply, gate, sum over M ----------------
#define GATED_GRID 625
__launch_bounds__(256)
__global__ void gated_kernel(const ushort* __restrict__ g,
                             const float* __restrict__ sc1, const float* __restrict__ sh1,
                             float* __restrict__ summed, float* __restrict__ stats2) {
    __shared__ float red[1024];
    const int t = threadIdx.x;
    const int sub = t & 15;        // channel quad: c0 = sub*4
    const int ag = t >> 4;         // atom slot 0..15
    const int c0 = sub * 4;

    float scF[4], shF[4], scC[4], shC[4];
#pragma unroll
    for (int q = 0; q < 4; q++) {
        scF[q] = sc1[c0 + q];      shF[q] = sh1[c0 + q];
        scC[q] = sc1[c0 + q + 64]; shC[q] = sh1[c0 + q + 64];
    }

    float pa[4] = {0, 0, 0, 0}, pb[4] = {0, 0, 0, 0};  // bn2 partials (channels c0..c0+3)

    for (int grp = blockIdx.x; grp < NN / 16; grp += GATED_GRID) {
        int a = grp * 16 + ag;
        float s[4] = {0, 0, 0, 0};
#pragma unroll
        for (int j = 0; j < MM; j++) {
            const ushort* rowp = g + ((size_t)a * MM + j) * GG;
            uint2 fv = *(const uint2*)&rowp[c0];
            uint2 cv = *(const uint2*)&rowp[c0 + 64];
            ushort hF[4] = {(ushort)(fv.x & 0xffff), (ushort)(fv.x >> 16),
                            (ushort)(fv.y & 0xffff), (ushort)(fv.y >> 16)};
            ushort hC[4] = {(ushort)(cv.x & 0xffff), (ushort)(cv.x >> 16),
                            (ushort)(cv.y & 0xffff), (ushort)(cv.y >> 16)};
#pragma unroll
            for (int q = 0; q < 4; q++) {
                float gF = bf2f(hF[q]) * scF[q] + shF[q];
                float gC = bf2f(hC[q]) * scC[q] + shC[q];
                s[q] += sigmoidf_(gF) * softplusf(gC);
            }
        }
        float4 o = make_float4(s[0], s[1], s[2], s[3]);
        *(float4*)&summed[(size_t)a * FF + c0] = o;
#pragma unroll
        for (int q = 0; q < 4; q++) { pa[q] += s[q]; pb[q] += s[q] * s[q]; }
    }

    // bn2 stats reduce: red[ag*64 + c]
#pragma unroll
    for (int q = 0; q < 4; q++) red[ag * 64 + c0 + q] = pa[q];
    __syncthreads();
    if (t < 64) {
        float ss = 0.f;
#pragma unroll
        for (int a2 = 0; a2 < 16; a2++) ss += red[a2 * 64 + t];
        atomicAdd(&stats2[t], ss);
    }
    __syncthreads();
#pragma unroll
    for (int q = 0; q < 4; q++) red[ag * 64 + c0 + q] = pb[q];
    __syncthreads();
    if (t < 64) {
        float ss = 0.f;
#pragma unroll
        for (int a2 = 0; a2 < 16; a2++) ss += red[a2 * 64 + t];
        atomicAdd(&stats2[64 + t], ss);
    }
}

// ---------------- legacy R4 two-pass conv (ws fallback) ----------------
template <int PASS>
__launch_bounds__(256, 2)
__global__ void conv_mfma(const ushort* __restrict__ xb, const float* __restrict__ nbr_fea,
                          const int* __restrict__ nidx, const ushort* __restrict__ wpk_l,
                          const float* __restrict__ fcb_l,
                          float* __restrict__ stats,
                          const float* __restrict__ sc1, const float* __restrict__ sh1,
                          float* __restrict__ summed, float* __restrict__ stats2) {
    __shared__ __align__(16) ushort As[TILE_ROWS * 192];
    __shared__ int nb[TILE_ROWS];
    __shared__ float gacc[TILE_ATOMS * FF];
    __shared__ float red[256];

    const int t = threadIdx.x;
    const int lane = t & 63;
    const int w = t >> 6;
    const int l15 = lane & 15;
    const int lg = lane >> 4;

    bf16x8 bfrag[2][6];
#pragma unroll
    for (int c2 = 0; c2 < 2; c2++)
#pragma unroll
        for (int kk = 0; kk < 6; kk++)
            bfrag[c2][kk] = *(const bf16x8*)&wpk_l[((((w + 4 * c2) * 6 + kk) * 64 + lane) * 8)];

    const int chF = w * 16 + l15;
    const int chC = chF + 64;
    const float bF = fcb_l[chF], bC = fcb_l[chC];
    float scF = 0.f, shF = 0.f, scC = 0.f, shC = 0.f;
    if (PASS == 1) { scF = sc1[chF]; shF = sh1[chF]; scC = sc1[chC]; shC = sh1[chC]; }

    float sAF = 0.f, sBF = 0.f, sAC = 0.f, sBC = 0.f;
    float s2a = 0.f, s2b = 0.f;

    for (int tile = blockIdx.x; tile < NTILES; tile += gridDim.x) {
        const int ebase = tile * TILE_ROWS;
        __syncthreads();
        if (t < TILE_ROWS) nb[t] = nidx[ebase + t];
        if (PASS == 1) { gacc[t] = 0.f; gacc[256 + t] = 0.f; }
        __syncthreads();

#pragma unroll
        for (int e = t; e < TILE_ROWS * SLOTS; e += 256) {
            int row = e / SLOTS;
            int slot = e - row * SLOTS;
            uint4 val;
            if (slot < 16) {
                int a = (slot < 8) ? (tile * TILE_ATOMS + row / 12) : nb[row];
                val = *(const uint4*)&xb[a * 64 + (slot & 7) * 8];
            } else {
                int kb = (slot - 16) * 8;
                const float* src = nbr_fea + (size_t)(ebase + row) * NBR + kb;
                ushort h[8];
#pragma unroll
                for (int i = 0; i < 8; i++)
                    h[i] = (kb + i < NBR) ? f2bf(src[i]) : (ushort)0;
                val.x = (uint)h[0] | ((uint)h[1] << 16);
                val.y = (uint)h[2] | ((uint)h[3] << 16);
                val.z = (uint)h[4] | ((uint)h[5] << 16);
                val.w = (uint)h[6] | ((uint)h[7] << 16);
            }
            *(uint4*)&As[row * 192 + ((slot ^ (row & 7)) * 8)] = val;
        }
        __syncthreads();

        f32x4 acc[6][2];
#pragma unroll
        for (int rf = 0; rf < 6; rf++)
#pragma unroll
            for (int c2 = 0; c2 < 2; c2++) acc[rf][c2] = (f32x4){0.f, 0.f, 0.f, 0.f};

#pragma unroll
        for (int kk = 0; kk < 6; kk++) {
#pragma unroll
            for (int rf = 0; rf < 6; rf++) {
                int row = rf * 16 + l15;
                int slot = kk * 4 + lg;
                bf16x8 a = *(const bf16x8*)&As[row * 192 + ((slot ^ (row & 7)) * 8)];
                acc[rf][0] = __builtin_amdgcn_mfma_f32_16x16x32_bf16(a, bfrag[0][kk], acc[rf][0], 0, 0, 0);
                acc[rf][1] = __builtin_amdgcn_mfma_f32_16x16x32_bf16(a, bfrag[1][kk], acc[rf][1], 0, 0, 0);
            }
        }

        if (PASS == 0) {
#pragma unroll
            for (int rf = 0; rf < 6; rf++)
#pragma unroll
                for (int q = 0; q < 4; q++) {
                    float gF = acc[rf][0][q] + bF;
                    float gC = acc[rf][1][q] + bC;
                    sAF += gF; sBF += gF * gF;
                    sAC += gC; sBC += gC * gC;
                }
        } else {
#pragma unroll
            for (int rf = 0; rf < 6; rf++) {
                int r0 = rf * 16 + lg * 4;
                float p = 0.f;
#pragma unroll
                for (int q = 0; q < 4; q++) {
                    float gF = (acc[rf][0][q] + bF) * scF + shF;
                    float gC = (acc[rf][1][q] + bC) * scC + shC;
                    p += sigmoidf_(gF) * softplusf(gC);
                }
                atomicAdd(&gacc[(r0 / 12) * FF + chF], p);
            }
            __syncthreads();
#pragma unroll
            for (int rep = 0; rep < 2; rep++) {
                int idx = rep * 256 + t;
                int a = idx >> 6, c = idx & 63;
                float sm = gacc[idx];
                summed[(tile * TILE_ATOMS + a) * FF + c] = sm;
                s2a += sm; s2b += sm * sm;
            }
        }
    }

    if (PASS == 0) {
        __syncthreads(); red[t] = sAF; __syncthreads();
        if (t < 64) {
            float s = 0.f;
#pragma unroll
            for (int g2 = 0; g2 < 4; g2++) s += red[(t >> 4) * 64 + g2 * 16 + (t & 15)];
            atomicAdd(&stats[t], s);
        }
        __syncthreads(); red[t] = sBF; __syncthreads();
        if (t < 64) {
            float s = 0.f;
#pragma unroll
            for (int g2 = 0; g2 < 4; g2++) s += red[(t >> 4) * 64 + g2 * 16 + (t & 15)];
            atomicAdd(&stats[128 + t], s);
        }
        __syncthreads(); red[t] = sAC; __syncthreads();
        if (t < 64) {
            float s = 0.f;
#pragma unroll
            for (int g2 = 0; g2 < 4; g2++) s += red[(t >> 4) * 64 + g2 * 16 + (t & 15)];
            atomicAdd(&stats[64 + t], s);
        }
        __syncthreads(); red[t] = sBC; __syncthreads();
        if (t < 64) {
            float s = 0.f;
#pragma unroll
            for (int g2 = 0; g2 < 4; g2++) s += red[(t >> 4) * 64 + g2 * 16 + (t & 15)];
            atomicAdd(&stats[192 + t], s);
        }
    } else {
        __syncthreads(); red[t] = s2a; __syncthreads();
        if (t < 64) {
            float s = red[t] + red[64 + t] + red[128 + t] + red[192 + t];
            atomicAdd(&stats2[t], s);
        }
        __syncthreads(); red[t] = s2b; __syncthreads();
        if (t < 64) {
            float s = red[t] + red[64 + t] + red[128 + t] + red[192 + t];
            atomicAdd(&stats2[64 + t], s);
        }
    }
}

// ---------------- bn finalize ----------------
__global__ void fin1_kernel(const float* __restrict__ stats, const float* __restrict__ g,
                            const float* __restrict__ b, float* __restrict__ sc, float* __restrict__ sh) {
    int c = threadIdx.x;  // 128
    const float inv = 1.f / (float)(NN * MM);
    float mu = stats[c] * inv;
    float var = stats[128 + c] * inv - mu * mu;
    float s = rsqrtf(var + EPSV) * g[c];
    sc[c] = s;
    sh[c] = b[c] - mu * s;
}

__global__ void fin2_kernel(const float* __restrict__ stats2, const float* __restrict__ g,
                            const float* __restrict__ b, float* __restrict__ sc, float* __restrict__ sh) {
    int c = threadIdx.x;  // 64
    const float inv = 1.f / (float)NN;
    float mu = stats2[c] * inv;
    float var = stats2[64 + c] * inv - mu * mu;
    float s = rsqrtf(var + EPSV) * g[c];
    sc[c] = s;
    sh[c] = b[c] - mu * s;
}

// ---------------- x = softplus(x + bn2(summed)) ; refresh xb ----------------
__global__ void update_x_kernel(float* __restrict__ x, ushort* __restrict__ xb,
                                const float* __restrict__ summed,
                                const float* __restrict__ sc2, const float* __restrict__ sh2) {
    for (int idx = blockIdx.x * blockDim.x + threadIdx.x; idx < NN * FF;
         idx += gridDim.x * blockDim.x) {
        int c = idx & 63;
        float v = softplusf(x[idx] + summed[idx] * sc2[c] + sh2[c]);
        x[idx] = v;
        xb[idx] = f2bf(v);
    }
}

// ---------------- segment pooling ----------------
__global__ void seg_pool_kernel(const float* __restrict__ x, const int* __restrict__ seg,
                                float* __restrict__ csum, float* __restrict__ ccnt) {
    for (int idx = blockIdx.x * blockDim.x + threadIdx.x; idx < NN * FF;
         idx += gridDim.x * blockDim.x) {
        int i = idx >> 6;
        int c = idx & 63;
        atomicAdd(&csum[seg[i] * FF + c], x[idx]);
        if (c == 0) atomicAdd(&ccnt[seg[i]], 1.f);
    }
}

// ---------------- per-crystal head ----------------
__global__ void head_kernel(const float* __restrict__ csum, const float* __restrict__ ccnt,
                            const float* __restrict__ c2fW, const float* __restrict__ c2fb,
                            const float* __restrict__ outW, const float* __restrict__ outb,
                            float* __restrict__ out) {
    __shared__ float pl[FF];
    __shared__ float red[HH];
    int c = blockIdx.x;
    int t = threadIdx.x;
    if (t < FF) {
        float cnt = fmaxf(ccnt[c], 1.f);
        pl[t] = softplusf(csum[c * FF + t] / cnt);
    }
    __syncthreads();
    float acc = c2fb[t];
    for (int f = 0; f < FF; f++) acc += pl[f] * c2fW[f * HH + t];
    red[t] = softplusf(acc) * outW[t];
    __syncthreads();
    for (int s = 64; s > 0; s >>= 1) {
        if (t < s) red[t] += red[t + s];
        __syncthreads();
    }
    if (t == 0) out[c] = red[0] + outb[0];
}

extern "C" void kernel_launch(void* const* d_in, const int* in_sizes, int n_in,
                              void* d_out, int out_size, void* d_ws, size_t ws_size,
                              hipStream_t stream) {
    const float* atom_fea = (const float*)d_in[0];
    const float* nbr_fea  = (const float*)d_in[1];
    const int*   nbr_idx  = (const int*)d_in[2];
    const int*   seg      = (const int*)d_in[3];
    const float* mask = (const float*)d_in[5];
    const float* embW = (const float*)d_in[6];
    const float* embb = (const float*)d_in[7];
    const float* fcW  = (const float*)d_in[8];
    const float* fcb  = (const float*)d_in[9];
    const float* bn1g = (const float*)d_in[10];
    const float* bn1b = (const float*)d_in[11];
    const float* bn2g = (const float*)d_in[12];
    const float* bn2b = (const float*)d_in[13];
    const float* c2fW = (const float*)d_in[14];
    const float* c2fb = (const float*)d_in[15];
    const float* outW = (const float*)d_in[16];
    const float* outb = (const float*)d_in[17];
    float* out = (float*)d_out;

    // ws layout (f32 region, then ushort region; ccnt adjacent to csum!)
    float* ws     = (float*)d_ws;
    float* x      = ws;                       // N*F
    float* summed = x + NN * FF;              // N*F
    float* csum   = summed + NN * FF;         // CC*FF
    float* ccnt   = csum + CC * FF;           // CC (+3 pad -> 3128)
    float* stats  = ccnt + 3128;              // 256
    float* stats2 = stats + 256;              // 128
    float* sc1    = stats2 + 128;             // 128
    float* sh1    = sc1 + 128;                // 128
    float* sc2    = sh1 + 128;                // 64
    float* sh2    = sc2 + 64;                 // 64
    ushort* xb    = (ushort*)(sh2 + 64);      // N*F bf16
    ushort* wpk   = xb + NN * FF;             // 3 * WPK_L
    ushort* nbrb  = wpk + 3 * WPK_L;          // N*M*64 bf16
    ushort* gbuf  = nbrb + (size_t)NN * MM * 64;  // N*M*128 bf16

    const size_t need_full =
        (size_t)((char*)(gbuf + (size_t)NN * MM * GG) - (char*)d_ws);
    const bool full = (ws_size >= need_full);

    packW_kernel<<<144, 64, 0, stream>>>(fcW, wpk);
    embed_kernel<<<2048, 256, 0, stream>>>(atom_fea, mask, embW, embb, x, xb);
    if (full) prepack_nbr<<<4096, 256, 0, stream>>>(nbr_fea, nbrb);

    for (int l = 0; l < NCONV; l++) {
        const ushort* wpk_l = wpk + l * WPK_L;
        hipMemsetAsync(stats, 0, (256 + 128) * sizeof(float), stream);
        if (full) {
            conv_g<<<2048, 256, 0, stream>>>(xb, nbrb, nbr_idx, wpk_l, fcb + l * GG,
                                             stats, gbuf);
            fin1_kernel<<<1, 128, 0, stream>>>(stats, bn1g + l * GG, bn1b + l * GG, sc1, sh1);
            gated_kernel<<<GATED_GRID, 256, 0, stream>>>(gbuf, sc1, sh1, summed, stats2);
        } else {
            conv_mfma<0><<<2048, 256, 0, stream>>>(xb, nbr_fea, nbr_idx, wpk_l, fcb + l * GG,
                                                   stats, nullptr, nullptr, nullptr, nullptr);
            fin1_kernel<<<1, 128, 0, stream>>>(stats, bn1g + l * GG, bn1b + l * GG, sc1, sh1);
            conv_mfma<1><<<2048, 256, 0, stream>>>(xb, nbr_fea, nbr_idx, wpk_l, fcb + l * GG,
                                                   nullptr, sc1, sh1, summed, stats2);
        }
        fin2_kernel<<<1, 64, 0, stream>>>(stats2, bn2g + l * FF, bn2b + l * FF, sc2, sh2);
        update_x_kernel<<<2048, 256, 0, stream>>>(x, xb, summed, sc2, sh2);
    }

    hipMemsetAsync(csum, 0, (CC * FF + CC) * sizeof(float), stream);
    seg_pool_kernel<<<2048, 256, 0, stream>>>(x, seg, csum, ccnt);
    head_kernel<<<CC, 128, 0, stream>>>(csum, ccnt, c2fW, c2fb, outW, outb, out);
}

// Round 6
// 1567.495 us; speedup vs baseline: 5.4171x; 1.4096x over previous
//
#include <hip/hip_runtime.h>
#include <hip/hip_bf16.h>

// CGCNN forward. R6: R5 + fast-transcendental gated kernel (HW v_exp/v_log),
// 4x grid for gated, and last-layer update_x fused with segment pooling.
//   conv_g: g = [xb_self | xb_nbr | nbrb] @ W + fcb (MFMA bf16, K=192),
//           round g->bf16, store, bn1 stats on ROUNDED values.
//   gated:  stream g, bn1 apply, sigmoid*softplus, sum over M -> summed; bn2 stats.
// Fallback to R4 two-pass recompute if ws_size too small.

#define NN    100000
#define MM    12
#define ORIG  92
#define FF    64
#define NBR   41
#define HH    128
#define NCONV 3
#define CC    3125
#define K2    169
#define GG    128
#define EPSV  1e-5f

#define TILE_ATOMS 8
#define TILE_ROWS  96                  // 8 atoms * 12 edges
#define NTILES     (NN / TILE_ATOMS)   // 12500
#define SLOTS      24                  // 24 * 16B = 384B = 192 bf16 per A row
#define WPK_L      (48 * 64 * 8)       // ushorts per layer of packed W

typedef __attribute__((ext_vector_type(8))) short bf16x8;
typedef __attribute__((ext_vector_type(4))) float f32x4;

__device__ __forceinline__ float softplusf(float v) {
    return fmaxf(v, 0.f) + log1pf(expf(-fabsf(v)));
}
__device__ __forceinline__ float sigmoidf_(float v) {
    return 1.f / (1.f + expf(-v));
}
// fast variants (HW v_exp_f32 / v_log_f32 via __expf/__logf); abs err ~1e-6,
// fine vs bf16-grade threshold. 1+e in (1,2] so __logf accuracy is safe.
__device__ __forceinline__ float softplus_fast(float v) {
    return fmaxf(v, 0.f) + __logf(1.f + __expf(-fabsf(v)));
}
__device__ __forceinline__ float sigmoid_fast(float v) {
    return 1.f / (1.f + __expf(-v));
}
__device__ __forceinline__ ushort f2bf(float f) {
    __hip_bfloat16 h = __float2bfloat16(f);
    return *(ushort*)&h;
}
__device__ __forceinline__ float bf2f(ushort h) {
    uint u = ((uint)h) << 16;
    return __uint_as_float(u);
}

// ---------------- embed: x = (atom_fea * mask) @ embW + embb ; also xb ----------------
__global__ void embed_kernel(const float* __restrict__ af, const float* __restrict__ mask,
                             const float* __restrict__ embW, const float* __restrict__ embb,
                             float* __restrict__ x, ushort* __restrict__ xb) {
    int t = threadIdx.x;
    int c = t & 63;
    int rs = t >> 6;
    float b = embb[c];
    for (int row = blockIdx.x * 4 + rs; row < NN; row += gridDim.x * 4) {
        float acc = b;
        for (int o = 0; o < ORIG; o++) {
            acc += af[row * ORIG + o] * (mask[o] * embW[o * FF + c]);
        }
        x[row * FF + c] = acc;
        xb[row * FF + c] = f2bf(acc);
    }
}

// ---------------- pack W into MFMA B-fragment order ----------------
__global__ void packW_kernel(const float* __restrict__ fcW, ushort* __restrict__ wpk) {
    int b = blockIdx.x;            // 0..143 = l*48 + cf*6 + kk
    int l = b / 48;
    int r = b - l * 48;
    int cf = r / 6;
    int kk = r - cf * 6;
    int lane = threadIdx.x;        // 0..63
    int c = cf * 16 + (lane & 15);
#pragma unroll
    for (int i = 0; i < 8; i++) {
        int k = kk * 32 + (lane >> 4) * 8 + i;
        float v = (k < K2) ? fcW[(l * K2 + k) * GG + c] : 0.f;
        wpk[((size_t)b * 64 + lane) * 8 + i] = f2bf(v);
    }
}

// ---------------- prepack nbr_fea -> bf16 padded to 64 ----------------
__global__ void prepack_nbr(const float* __restrict__ nbr_fea, ushort* __restrict__ nbrb) {
    const size_t total = (size_t)NN * MM * 8;   // uint4 units
    for (size_t u = (size_t)blockIdx.x * blockDim.x + threadIdx.x; u < total;
         u += (size_t)gridDim.x * blockDim.x) {
        size_t row = u >> 3;
        int u4 = (int)(u & 7);
        int kb = u4 * 8;
        const float* src = nbr_fea + row * NBR + kb;
        ushort h[8];
#pragma unroll
        for (int i = 0; i < 8; i++)
            h[i] = (kb + i < NBR) ? f2bf(src[i]) : (ushort)0;
        uint4 val;
        val.x = (uint)h[0] | ((uint)h[1] << 16);
        val.y = (uint)h[2] | ((uint)h[3] << 16);
        val.z = (uint)h[4] | ((uint)h[5] << 16);
        val.w = (uint)h[6] | ((uint)h[7] << 16);
        ((uint4*)nbrb)[u] = val;
    }
}

// ---------------- conv_g: MFMA GEMM + g store + bn1 stats ----------------
__launch_bounds__(256, 4)
__global__ void conv_g(const ushort* __restrict__ xb, const ushort* __restrict__ nbrb,
                       const int* __restrict__ nidx, const ushort* __restrict__ wpk_l,
                       const float* __restrict__ fcb_l,
                       float* __restrict__ stats, ushort* __restrict__ g) {
    __shared__ __align__(16) ushort As[TILE_ROWS * 192];   // 36.9 KB (also gb repack)
    __shared__ int nb[TILE_ROWS];
    __shared__ float red[256];
    ushort* gb = As;   // reused after MFMA (barrier-protected)

    const int t = threadIdx.x;
    const int lane = t & 63;
    const int w = t >> 6;
    const int l15 = lane & 15;
    const int lg = lane >> 4;

    bf16x8 bfrag[2][6];
#pragma unroll
    for (int c2 = 0; c2 < 2; c2++)
#pragma unroll
        for (int kk = 0; kk < 6; kk++)
            bfrag[c2][kk] = *(const bf16x8*)&wpk_l[((((w + 4 * c2) * 6 + kk) * 64 + lane) * 8)];

    const int chF = w * 16 + l15;
    const int chC = chF + 64;
    const float bF = fcb_l[chF], bC = fcb_l[chC];

    float sAF = 0.f, sBF = 0.f, sAC = 0.f, sBC = 0.f;

    for (int tile = blockIdx.x; tile < NTILES; tile += gridDim.x) {
        const int ebase = tile * TILE_ROWS;
        __syncthreads();   // protect LDS (As/gb, nb) from previous tile
        if (t < TILE_ROWS) nb[t] = nidx[ebase + t];
        __syncthreads();

        // stage A: all uint4 copies
#pragma unroll
        for (int e = t; e < TILE_ROWS * SLOTS; e += 256) {  // 9 iters exact
            int row = e / SLOTS;
            int slot = e - row * SLOTS;
            const uint4* src;
            if (slot < 8)
                src = (const uint4*)&xb[(tile * TILE_ATOMS + row / 12) * 64 + slot * 8];
            else if (slot < 16)
                src = (const uint4*)&xb[nb[row] * 64 + (slot - 8) * 8];
            else
                src = (const uint4*)&nbrb[(size_t)(ebase + row) * 64 + (slot - 16) * 8];
            *(uint4*)&As[row * 192 + ((slot ^ (row & 7)) * 8)] = *src;
        }
        __syncthreads();

        f32x4 acc[6][2];
#pragma unroll
        for (int rf = 0; rf < 6; rf++)
#pragma unroll
            for (int c2 = 0; c2 < 2; c2++) acc[rf][c2] = (f32x4){0.f, 0.f, 0.f, 0.f};

#pragma unroll
        for (int kk = 0; kk < 6; kk++) {
#pragma unroll
            for (int rf = 0; rf < 6; rf++) {
                int row = rf * 16 + l15;
                int slot = kk * 4 + lg;
                bf16x8 a = *(const bf16x8*)&As[row * 192 + ((slot ^ (row & 7)) * 8)];
                acc[rf][0] = __builtin_amdgcn_mfma_f32_16x16x32_bf16(a, bfrag[0][kk], acc[rf][0], 0, 0, 0);
                acc[rf][1] = __builtin_amdgcn_mfma_f32_16x16x32_bf16(a, bfrag[1][kk], acc[rf][1], 0, 0, 0);
            }
        }
        __syncthreads();   // all A-frag reads done before gb overwrite

        // epilogue: round to bf16, stats on rounded values, swizzled LDS write
#pragma unroll
        for (int rf = 0; rf < 6; rf++)
#pragma unroll
            for (int q = 0; q < 4; q++) {
                int row = rf * 16 + lg * 4 + q;
                int swz = ((row >> 2) & 3) << 4;
                ushort hF = f2bf(acc[rf][0][q] + bF);
                ushort hC = f2bf(acc[rf][1][q] + bC);
                float gF = bf2f(hF), gC = bf2f(hC);
                sAF += gF; sBF += gF * gF;
                sAC += gC; sBC += gC * gC;
                gb[row * GG + (chF ^ swz)] = hF;
                gb[row * GG + (chC ^ swz)] = hC;
            }
        __syncthreads();

        // copy gb -> g (coalesced uint4)
        const uint4* gbu = (const uint4*)gb;
#pragma unroll
        for (int i = 0; i < 6; i++) {   // 1536 uint4 = 6*256
            int idx = i * 256 + t;
            int row = idx >> 4;
            int c8 = idx & 15;
            uint4 v = gbu[row * 16 + (c8 ^ (((row >> 2) & 3) << 1))];
            *(uint4*)&g[((size_t)(ebase + row)) * GG + c8 * 8] = v;
        }
    }

    // ------- end-of-kernel stats reduction -------
    __syncthreads(); red[t] = sAF; __syncthreads();
    if (t < 64) {
        float s = 0.f;
#pragma unroll
        for (int g2 = 0; g2 < 4; g2++) s += red[(t >> 4) * 64 + g2 * 16 + (t & 15)];
        atomicAdd(&stats[t], s);
    }
    __syncthreads(); red[t] = sBF; __syncthreads();
    if (t < 64) {
        float s = 0.f;
#pragma unroll
        for (int g2 = 0; g2 < 4; g2++) s += red[(t >> 4) * 64 + g2 * 16 + (t & 15)];
        atomicAdd(&stats[128 + t], s);
    }
    __syncthreads(); red[t] = sAC; __syncthreads();
    if (t < 64) {
        float s = 0.f;
#pragma unroll
        for (int g2 = 0; g2 < 4; g2++) s += red[(t >> 4) * 64 + g2 * 16 + (t & 15)];
        atomicAdd(&stats[64 + t], s);
    }
    __syncthreads(); red[t] = sBC; __syncthreads();
    if (t < 64) {
        float s = 0.f;
#pragma unroll
        for (int g2 = 0; g2 < 4; g2++) s += red[(t >> 4) * 64 + g2 * 16 + (t & 15)];
        atomicAdd(&stats[192 + t], s);
    }
}

// ---------------- gated: stream g, bn1 apply, gate, sum over M ----------------
#define GATED_GRID 2500
__launch_bounds__(256)
__global__ void gated_kernel(const ushort* __restrict__ g,
                             const float* __restrict__ sc1, const float* __restrict__ sh1,
                             float* __restrict__ summed, float* __restrict__ stats2) {
    __shared__ float red[1024];
    const int t = threadIdx.x;
    const int sub = t & 15;        // channel quad: c0 = sub*4
    const int ag = t >> 4;         // atom slot 0..15
    const int c0 = sub * 4;

    float scF[4], shF[4], scC[4], shC[4];
#pragma unroll
    for (int q = 0; q < 4; q++) {
        scF[q] = sc1[c0 + q];      shF[q] = sh1[c0 + q];
        scC[q] = sc1[c0 + q + 64]; shC[q] = sh1[c0 + q + 64];
    }

    float pa[4] = {0, 0, 0, 0}, pb[4] = {0, 0, 0, 0};

    for (int grp = blockIdx.x; grp < NN / 16; grp += GATED_GRID) {
        int a = grp * 16 + ag;
        float s[4] = {0, 0, 0, 0};
#pragma unroll
        for (int j = 0; j < MM; j++) {
            const ushort* rowp = g + ((size_t)a * MM + j) * GG;
            uint2 fv = *(const uint2*)&rowp[c0];
            uint2 cv = *(const uint2*)&rowp[c0 + 64];
            ushort hF[4] = {(ushort)(fv.x & 0xffff), (ushort)(fv.x >> 16),
                            (ushort)(fv.y & 0xffff), (ushort)(fv.y >> 16)};
            ushort hC[4] = {(ushort)(cv.x & 0xffff), (ushort)(cv.x >> 16),
                            (ushort)(cv.y & 0xffff), (ushort)(cv.y >> 16)};
#pragma unroll
            for (int q = 0; q < 4; q++) {
                float gF = bf2f(hF[q]) * scF[q] + shF[q];
                float gC = bf2f(hC[q]) * scC[q] + shC[q];
                s[q] += sigmoid_fast(gF) * softplus_fast(gC);
            }
        }
        float4 o = make_float4(s[0], s[1], s[2], s[3]);
        *(float4*)&summed[(size_t)a * FF + c0] = o;
#pragma unroll
        for (int q = 0; q < 4; q++) { pa[q] += s[q]; pb[q] += s[q] * s[q]; }
    }

    // bn2 stats reduce: red[ag*64 + c]
#pragma unroll
    for (int q = 0; q < 4; q++) red[ag * 64 + c0 + q] = pa[q];
    __syncthreads();
    if (t < 64) {
        float ss = 0.f;
#pragma unroll
        for (int a2 = 0; a2 < 16; a2++) ss += red[a2 * 64 + t];
        atomicAdd(&stats2[t], ss);
    }
    __syncthreads();
#pragma unroll
    for (int q = 0; q < 4; q++) red[ag * 64 + c0 + q] = pb[q];
    __syncthreads();
    if (t < 64) {
        float ss = 0.f;
#pragma unroll
        for (int a2 = 0; a2 < 16; a2++) ss += red[a2 * 64 + t];
        atomicAdd(&stats2[64 + t], ss);
    }
}

// ---------------- legacy R4 two-pass conv (ws fallback) ----------------
template <int PASS>
__launch_bounds__(256, 2)
__global__ void conv_mfma(const ushort* __restrict__ xb, const float* __restrict__ nbr_fea,
                          const int* __restrict__ nidx, const ushort* __restrict__ wpk_l,
                          const float* __restrict__ fcb_l,
                          float* __restrict__ stats,
                          const float* __restrict__ sc1, const float* __restrict__ sh1,
                          float* __restrict__ summed, float* __restrict__ stats2) {
    __shared__ __align__(16) ushort As[TILE_ROWS * 192];
    __shared__ int nb[TILE_ROWS];
    __shared__ float gacc[TILE_ATOMS * FF];
    __shared__ float red[256];

    const int t = threadIdx.x;
    const int lane = t & 63;
    const int w = t >> 6;
    const int l15 = lane & 15;
    const int lg = lane >> 4;

    bf16x8 bfrag[2][6];
#pragma unroll
    for (int c2 = 0; c2 < 2; c2++)
#pragma unroll
        for (int kk = 0; kk < 6; kk++)
            bfrag[c2][kk] = *(const bf16x8*)&wpk_l[((((w + 4 * c2) * 6 + kk) * 64 + lane) * 8)];

    const int chF = w * 16 + l15;
    const int chC = chF + 64;
    const float bF = fcb_l[chF], bC = fcb_l[chC];
    float scF = 0.f, shF = 0.f, scC = 0.f, shC = 0.f;
    if (PASS == 1) { scF = sc1[chF]; shF = sh1[chF]; scC = sc1[chC]; shC = sh1[chC]; }

    float sAF = 0.f, sBF = 0.f, sAC = 0.f, sBC = 0.f;
    float s2a = 0.f, s2b = 0.f;

    for (int tile = blockIdx.x; tile < NTILES; tile += gridDim.x) {
        const int ebase = tile * TILE_ROWS;
        __syncthreads();
        if (t < TILE_ROWS) nb[t] = nidx[ebase + t];
        if (PASS == 1) { gacc[t] = 0.f; gacc[256 + t] = 0.f; }
        __syncthreads();

#pragma unroll
        for (int e = t; e < TILE_ROWS * SLOTS; e += 256) {
            int row = e / SLOTS;
            int slot = e - row * SLOTS;
            uint4 val;
            if (slot < 16) {
                int a = (slot < 8) ? (tile * TILE_ATOMS + row / 12) : nb[row];
                val = *(const uint4*)&xb[a * 64 + (slot & 7) * 8];
            } else {
                int kb = (slot - 16) * 8;
                const float* src = nbr_fea + (size_t)(ebase + row) * NBR + kb;
                ushort h[8];
#pragma unroll
                for (int i = 0; i < 8; i++)
                    h[i] = (kb + i < NBR) ? f2bf(src[i]) : (ushort)0;
                val.x = (uint)h[0] | ((uint)h[1] << 16);
                val.y = (uint)h[2] | ((uint)h[3] << 16);
                val.z = (uint)h[4] | ((uint)h[5] << 16);
                val.w = (uint)h[6] | ((uint)h[7] << 16);
            }
            *(uint4*)&As[row * 192 + ((slot ^ (row & 7)) * 8)] = val;
        }
        __syncthreads();

        f32x4 acc[6][2];
#pragma unroll
        for (int rf = 0; rf < 6; rf++)
#pragma unroll
            for (int c2 = 0; c2 < 2; c2++) acc[rf][c2] = (f32x4){0.f, 0.f, 0.f, 0.f};

#pragma unroll
        for (int kk = 0; kk < 6; kk++) {
#pragma unroll
            for (int rf = 0; rf < 6; rf++) {
                int row = rf * 16 + l15;
                int slot = kk * 4 + lg;
                bf16x8 a = *(const bf16x8*)&As[row * 192 + ((slot ^ (row & 7)) * 8)];
                acc[rf][0] = __builtin_amdgcn_mfma_f32_16x16x32_bf16(a, bfrag[0][kk], acc[rf][0], 0, 0, 0);
                acc[rf][1] = __builtin_amdgcn_mfma_f32_16x16x32_bf16(a, bfrag[1][kk], acc[rf][1], 0, 0, 0);
            }
        }

        if (PASS == 0) {
#pragma unroll
            for (int rf = 0; rf < 6; rf++)
#pragma unroll
                for (int q = 0; q < 4; q++) {
                    float gF = acc[rf][0][q] + bF;
                    float gC = acc[rf][1][q] + bC;
                    sAF += gF; sBF += gF * gF;
                    sAC += gC; sBC += gC * gC;
                }
        } else {
#pragma unroll
            for (int rf = 0; rf < 6; rf++) {
                int r0 = rf * 16 + lg * 4;
                float p = 0.f;
#pragma unroll
                for (int q = 0; q < 4; q++) {
                    float gF = (acc[rf][0][q] + bF) * scF + shF;
                    float gC = (acc[rf][1][q] + bC) * scC + shC;
                    p += sigmoidf_(gF) * softplusf(gC);
                }
                atomicAdd(&gacc[(r0 / 12) * FF + chF], p);
            }
            __syncthreads();
#pragma unroll
            for (int rep = 0; rep < 2; rep++) {
                int idx = rep * 256 + t;
                int a = idx >> 6, c = idx & 63;
                float sm = gacc[idx];
                summed[(tile * TILE_ATOMS + a) * FF + c] = sm;
                s2a += sm; s2b += sm * sm;
            }
        }
    }

    if (PASS == 0) {
        __syncthreads(); red[t] = sAF; __syncthreads();
        if (t < 64) {
            float s = 0.f;
#pragma unroll
            for (int g2 = 0; g2 < 4; g2++) s += red[(t >> 4) * 64 + g2 * 16 + (t & 15)];
            atomicAdd(&stats[t], s);
        }
        __syncthreads(); red[t] = sBF; __syncthreads();
        if (t < 64) {
            float s = 0.f;
#pragma unroll
            for (int g2 = 0; g2 < 4; g2++) s += red[(t >> 4) * 64 + g2 * 16 + (t & 15)];
            atomicAdd(&stats[128 + t], s);
        }
        __syncthreads(); red[t] = sAC; __syncthreads();
        if (t < 64) {
            float s = 0.f;
#pragma unroll
            for (int g2 = 0; g2 < 4; g2++) s += red[(t >> 4) * 64 + g2 * 16 + (t & 15)];
            atomicAdd(&stats[64 + t], s);
        }
        __syncthreads(); red[t] = sBC; __syncthreads();
        if (t < 64) {
            float s = 0.f;
#pragma unroll
            for (int g2 = 0; g2 < 4; g2++) s += red[(t >> 4) * 64 + g2 * 16 + (t & 15)];
            atomicAdd(&stats[192 + t], s);
        }
    } else {
        __syncthreads(); red[t] = s2a; __syncthreads();
        if (t < 64) {
            float s = red[t] + red[64 + t] + red[128 + t] + red[192 + t];
            atomicAdd(&stats2[t], s);
        }
        __syncthreads(); red[t] = s2b; __syncthreads();
        if (t < 64) {
            float s = red[t] + red[64 + t] + red[128 + t] + red[192 + t];
            atomicAdd(&stats2[64 + t], s);
        }
    }
}

// ---------------- bn finalize ----------------
__global__ void fin1_kernel(const float* __restrict__ stats, const float* __restrict__ g,
                            const float* __restrict__ b, float* __restrict__ sc, float* __restrict__ sh) {
    int c = threadIdx.x;  // 128
    const float inv = 1.f / (float)(NN * MM);
    float mu = stats[c] * inv;
    float var = stats[128 + c] * inv - mu * mu;
    float s = rsqrtf(var + EPSV) * g[c];
    sc[c] = s;
    sh[c] = b[c] - mu * s;
}

__global__ void fin2_kernel(const float* __restrict__ stats2, const float* __restrict__ g,
                            const float* __restrict__ b, float* __restrict__ sc, float* __restrict__ sh) {
    int c = threadIdx.x;  // 64
    const float inv = 1.f / (float)NN;
    float mu = stats2[c] * inv;
    float var = stats2[64 + c] * inv - mu * mu;
    float s = rsqrtf(var + EPSV) * g[c];
    sc[c] = s;
    sh[c] = b[c] - mu * s;
}

// ---------------- x = softplus(x + bn2(summed)) ; refresh xb ----------------
__global__ void update_x_kernel(float* __restrict__ x, ushort* __restrict__ xb,
                                const float* __restrict__ summed,
                                const float* __restrict__ sc2, const float* __restrict__ sh2) {
    for (int idx = blockIdx.x * blockDim.x + threadIdx.x; idx < NN * FF;
         idx += gridDim.x * blockDim.x) {
        int c = idx & 63;
        float v = softplusf(x[idx] + summed[idx] * sc2[c] + sh2[c]);
        x[idx] = v;
        xb[idx] = f2bf(v);
    }
}

// ---------------- last layer: update_x fused with segment pooling ----------------
__global__ void update_x_pool_kernel(const float* __restrict__ x,
                                     const float* __restrict__ summed,
                                     const float* __restrict__ sc2, const float* __restrict__ sh2,
                                     const int* __restrict__ seg,
                                     float* __restrict__ csum, float* __restrict__ ccnt) {
    for (int idx = blockIdx.x * blockDim.x + threadIdx.x; idx < NN * FF;
         idx += gridDim.x * blockDim.x) {
        int i = idx >> 6;
        int c = idx & 63;
        float v = softplusf(x[idx] + summed[idx] * sc2[c] + sh2[c]);
        atomicAdd(&csum[seg[i] * FF + c], v);
        if (c == 0) atomicAdd(&ccnt[seg[i]], 1.f);
    }
}

// ---------------- per-crystal head ----------------
__global__ void head_kernel(const float* __restrict__ csum, const float* __restrict__ ccnt,
                            const float* __restrict__ c2fW, const float* __restrict__ c2fb,
                            const float* __restrict__ outW, const float* __restrict__ outb,
                            float* __restrict__ out) {
    __shared__ float pl[FF];
    __shared__ float red[HH];
    int c = blockIdx.x;
    int t = threadIdx.x;
    if (t < FF) {
        float cnt = fmaxf(ccnt[c], 1.f);
        pl[t] = softplusf(csum[c * FF + t] / cnt);
    }
    __syncthreads();
    float acc = c2fb[t];
    for (int f = 0; f < FF; f++) acc += pl[f] * c2fW[f * HH + t];
    red[t] = softplusf(acc) * outW[t];
    __syncthreads();
    for (int s = 64; s > 0; s >>= 1) {
        if (t < s) red[t] += red[t + s];
        __syncthreads();
    }
    if (t == 0) out[c] = red[0] + outb[0];
}

extern "C" void kernel_launch(void* const* d_in, const int* in_sizes, int n_in,
                              void* d_out, int out_size, void* d_ws, size_t ws_size,
                              hipStream_t stream) {
    const float* atom_fea = (const float*)d_in[0];
    const float* nbr_fea  = (const float*)d_in[1];
    const int*   nbr_idx  = (const int*)d_in[2];
    const int*   seg      = (const int*)d_in[3];
    const float* mask = (const float*)d_in[5];
    const float* embW = (const float*)d_in[6];
    const float* embb = (const float*)d_in[7];
    const float* fcW  = (const float*)d_in[8];
    const float* fcb  = (const float*)d_in[9];
    const float* bn1g = (const float*)d_in[10];
    const float* bn1b = (const float*)d_in[11];
    const float* bn2g = (const float*)d_in[12];
    const float* bn2b = (const float*)d_in[13];
    const float* c2fW = (const float*)d_in[14];
    const float* c2fb = (const float*)d_in[15];
    const float* outW = (const float*)d_in[16];
    const float* outb = (const float*)d_in[17];
    float* out = (float*)d_out;

    // ws layout (f32 region, then ushort region; ccnt adjacent to csum!)
    float* ws     = (float*)d_ws;
    float* x      = ws;                       // N*F
    float* summed = x + NN * FF;              // N*F
    float* csum   = summed + NN * FF;         // CC*FF
    float* ccnt   = csum + CC * FF;           // CC (+3 pad -> 3128)
    float* stats  = ccnt + 3128;              // 256
    float* stats2 = stats + 256;              // 128
    float* sc1    = stats2 + 128;             // 128
    float* sh1    = sc1 + 128;                // 128
    float* sc2    = sh1 + 128;                // 64
    float* sh2    = sc2 + 64;                 // 64
    ushort* xb    = (ushort*)(sh2 + 64);      // N*F bf16
    ushort* wpk   = xb + NN * FF;             // 3 * WPK_L
    ushort* nbrb  = wpk + 3 * WPK_L;          // N*M*64 bf16
    ushort* gbuf  = nbrb + (size_t)NN * MM * 64;  // N*M*128 bf16

    const size_t need_full =
        (size_t)((char*)(gbuf + (size_t)NN * MM * GG) - (char*)d_ws);
    const bool full = (ws_size >= need_full);

    packW_kernel<<<144, 64, 0, stream>>>(fcW, wpk);
    embed_kernel<<<2048, 256, 0, stream>>>(atom_fea, mask, embW, embb, x, xb);
    if (full) prepack_nbr<<<4096, 256, 0, stream>>>(nbr_fea, nbrb);
    hipMemsetAsync(csum, 0, (CC * FF + CC) * sizeof(float), stream);

    for (int l = 0; l < NCONV; l++) {
        const ushort* wpk_l = wpk + l * WPK_L;
        hipMemsetAsync(stats, 0, (256 + 128) * sizeof(float), stream);
        if (full) {
            conv_g<<<2048, 256, 0, stream>>>(xb, nbrb, nbr_idx, wpk_l, fcb + l * GG,
                                             stats, gbuf);
            fin1_kernel<<<1, 128, 0, stream>>>(stats, bn1g + l * GG, bn1b + l * GG, sc1, sh1);
            gated_kernel<<<GATED_GRID, 256, 0, stream>>>(gbuf, sc1, sh1, summed, stats2);
        } else {
            conv_mfma<0><<<2048, 256, 0, stream>>>(xb, nbr_fea, nbr_idx, wpk_l, fcb + l * GG,
                                                   stats, nullptr, nullptr, nullptr, nullptr);
            fin1_kernel<<<1, 128, 0, stream>>>(stats, bn1g + l * GG, bn1b + l * GG, sc1, sh1);
            conv_mfma<1><<<2048, 256, 0, stream>>>(xb, nbr_fea, nbr_idx, wpk_l, fcb + l * GG,
                                                   nullptr, sc1, sh1, summed, stats2);
        }
        fin2_kernel<<<1, 64, 0, stream>>>(stats2, bn2g + l * FF, bn2b + l * FF, sc2, sh2);
        if (l < NCONV - 1) {
            update_x_kernel<<<2048, 256, 0, stream>>>(x, xb, summed, sc2, sh2);
        } else {
            update_x_pool_kernel<<<2048, 256, 0, stream>>>(x, summed, sc2, sh2,
                                                           seg, csum, ccnt);
        }
    }

    head_kernel<<<CC, 128, 0, stream>>>(csum, ccnt, c2fW, c2fb, outW, outb, out);
}

// Round 7
// 1364.615 us; speedup vs baseline: 6.2225x; 1.1487x over previous
//
#include <hip/hip_runtime.h>
#include <hip/hip_bf16.h>

// CGCNN forward. R7: g stored in RAW MFMA D-fragment layout (no transpose),
// with tile row permutation row = j*8 + a_loc so gated's atom-sum is one
// shfl_xor(32). conv_g epilogue: direct coalesced dwordx2 stores from acc.
//   conv_g: g = [xb_self | xb_nbr | nbrb] @ W + fcb (MFMA bf16, K=192),
//           bf16-round, store raw-layout, bn1 stats on ROUNDED values.
//   gated:  read g raw-layout, bn1 apply, sigmoid*softplus, sum over j
//           (lane-local + xor32), write summed; bn2 stats.
// Fallback to R4 two-pass recompute if ws_size too small.

#define NN    100000
#define MM    12
#define ORIG  92
#define FF    64
#define NBR   41
#define HH    128
#define NCONV 3
#define CC    3125
#define K2    169
#define GG    128
#define EPSV  1e-5f

#define TILE_ATOMS 8
#define TILE_ROWS  96                  // 8 atoms * 12 edges
#define NTILES     (NN / TILE_ATOMS)   // 12500
#define SLOTS      24                  // 24 * 16B = 384B = 192 bf16 per A row
#define WPK_L      (48 * 64 * 8)       // ushorts per layer of packed W
#define GRAW_TILE  (4 * 12 * 64 * 4)   // ushorts of raw g per tile (=12288)

typedef __attribute__((ext_vector_type(8))) short bf16x8;
typedef __attribute__((ext_vector_type(4))) float f32x4;

__device__ __forceinline__ float softplusf(float v) {
    return fmaxf(v, 0.f) + log1pf(expf(-fabsf(v)));
}
__device__ __forceinline__ float sigmoidf_(float v) {
    return 1.f / (1.f + expf(-v));
}
__device__ __forceinline__ float softplus_fast(float v) {
    return fmaxf(v, 0.f) + __logf(1.f + __expf(-fabsf(v)));
}
__device__ __forceinline__ float sigmoid_fast(float v) {
    return 1.f / (1.f + __expf(-v));
}
__device__ __forceinline__ ushort f2bf(float f) {
    __hip_bfloat16 h = __float2bfloat16(f);
    return *(ushort*)&h;
}
__device__ __forceinline__ float bf2f(ushort h) {
    uint u = ((uint)h) << 16;
    return __uint_as_float(u);
}

// ---------------- embed: x = (atom_fea * mask) @ embW + embb ; also xb ----------------
__global__ void embed_kernel(const float* __restrict__ af, const float* __restrict__ mask,
                             const float* __restrict__ embW, const float* __restrict__ embb,
                             float* __restrict__ x, ushort* __restrict__ xb) {
    int t = threadIdx.x;
    int c = t & 63;
    int rs = t >> 6;
    float b = embb[c];
    for (int row = blockIdx.x * 4 + rs; row < NN; row += gridDim.x * 4) {
        float acc = b;
        for (int o = 0; o < ORIG; o++) {
            acc += af[row * ORIG + o] * (mask[o] * embW[o * FF + c]);
        }
        x[row * FF + c] = acc;
        xb[row * FF + c] = f2bf(acc);
    }
}

// ---------------- pack W into MFMA B-fragment order ----------------
__global__ void packW_kernel(const float* __restrict__ fcW, ushort* __restrict__ wpk) {
    int b = blockIdx.x;            // 0..143 = l*48 + cf*6 + kk
    int l = b / 48;
    int r = b - l * 48;
    int cf = r / 6;
    int kk = r - cf * 6;
    int lane = threadIdx.x;        // 0..63
    int c = cf * 16 + (lane & 15);
#pragma unroll
    for (int i = 0; i < 8; i++) {
        int k = kk * 32 + (lane >> 4) * 8 + i;
        float v = (k < K2) ? fcW[(l * K2 + k) * GG + c] : 0.f;
        wpk[((size_t)b * 64 + lane) * 8 + i] = f2bf(v);
    }
}

// ---------------- prepack nbr_fea -> bf16 padded to 64 ----------------
__global__ void prepack_nbr(const float* __restrict__ nbr_fea, ushort* __restrict__ nbrb) {
    const size_t total = (size_t)NN * MM * 8;   // uint4 units
    for (size_t u = (size_t)blockIdx.x * blockDim.x + threadIdx.x; u < total;
         u += (size_t)gridDim.x * blockDim.x) {
        size_t row = u >> 3;
        int u4 = (int)(u & 7);
        int kb = u4 * 8;
        const float* src = nbr_fea + row * NBR + kb;
        ushort h[8];
#pragma unroll
        for (int i = 0; i < 8; i++)
            h[i] = (kb + i < NBR) ? f2bf(src[i]) : (ushort)0;
        uint4 val;
        val.x = (uint)h[0] | ((uint)h[1] << 16);
        val.y = (uint)h[2] | ((uint)h[3] << 16);
        val.z = (uint)h[4] | ((uint)h[5] << 16);
        val.w = (uint)h[6] | ((uint)h[7] << 16);
        ((uint4*)nbrb)[u] = val;
    }
}

// ---------------- conv_g: MFMA GEMM + raw-layout g store + bn1 stats ----------------
// LDS row r <-> (a_loc = r&7, j = r>>3). D-frag: row = rf*16 + lg*4 + q.
// Raw g offset (ushorts): (((tile*4 + w)*12 + rf*2 + c2)*64 + lane)*4, q packed in 4.
__launch_bounds__(256, 4)
__global__ void conv_g(const ushort* __restrict__ xb, const ushort* __restrict__ nbrb,
                       const int* __restrict__ nidx, const ushort* __restrict__ wpk_l,
                       const float* __restrict__ fcb_l,
                       float* __restrict__ stats, ushort* __restrict__ g) {
    __shared__ __align__(16) ushort As[TILE_ROWS * 192];   // 36.9 KB
    __shared__ int nb[TILE_ROWS];
    __shared__ float red[256];

    const int t = threadIdx.x;
    const int lane = t & 63;
    const int w = t >> 6;
    const int l15 = lane & 15;
    const int lg = lane >> 4;

    bf16x8 bfrag[2][6];
#pragma unroll
    for (int c2 = 0; c2 < 2; c2++)
#pragma unroll
        for (int kk = 0; kk < 6; kk++)
            bfrag[c2][kk] = *(const bf16x8*)&wpk_l[((((w + 4 * c2) * 6 + kk) * 64 + lane) * 8)];

    const int chF = w * 16 + l15;
    const int chC = chF + 64;
    const float bF = fcb_l[chF], bC = fcb_l[chC];

    float sAF = 0.f, sBF = 0.f, sAC = 0.f, sBC = 0.f;

    for (int tile = blockIdx.x; tile < NTILES; tile += gridDim.x) {
        const int ebase = tile * TILE_ROWS;
        __syncthreads();   // protect As/nb from previous tile
        if (t < TILE_ROWS) nb[t] = nidx[ebase + (t & 7) * MM + (t >> 3)];
        __syncthreads();

        // stage A rows (permuted): row r = j*8 + a_loc
#pragma unroll
        for (int e = t; e < TILE_ROWS * SLOTS; e += 256) {  // 9 iters exact
            int row = e / SLOTS;
            int slot = e - row * SLOTS;
            int a_loc = row & 7;
            int j = row >> 3;
            const uint4* src;
            if (slot < 8)
                src = (const uint4*)&xb[(tile * TILE_ATOMS + a_loc) * 64 + slot * 8];
            else if (slot < 16)
                src = (const uint4*)&xb[nb[row] * 64 + (slot - 8) * 8];
            else
                src = (const uint4*)&nbrb[(size_t)(ebase + a_loc * MM + j) * 64 + (slot - 16) * 8];
            *(uint4*)&As[row * 192 + ((slot ^ (row & 7)) * 8)] = *src;
        }
        __syncthreads();

        f32x4 acc[6][2];
#pragma unroll
        for (int rf = 0; rf < 6; rf++)
#pragma unroll
            for (int c2 = 0; c2 < 2; c2++) acc[rf][c2] = (f32x4){0.f, 0.f, 0.f, 0.f};

#pragma unroll
        for (int kk = 0; kk < 6; kk++) {
#pragma unroll
            for (int rf = 0; rf < 6; rf++) {
                int row = rf * 16 + l15;
                int slot = kk * 4 + lg;
                bf16x8 a = *(const bf16x8*)&As[row * 192 + ((slot ^ (row & 7)) * 8)];
                acc[rf][0] = __builtin_amdgcn_mfma_f32_16x16x32_bf16(a, bfrag[0][kk], acc[rf][0], 0, 0, 0);
                acc[rf][1] = __builtin_amdgcn_mfma_f32_16x16x32_bf16(a, bfrag[1][kk], acc[rf][1], 0, 0, 0);
            }
        }

        // epilogue: bf16 round, stats on rounded, direct coalesced stores
#pragma unroll
        for (int rf = 0; rf < 6; rf++) {
            ushort hF[4], hC[4];
#pragma unroll
            for (int q = 0; q < 4; q++) {
                hF[q] = f2bf(acc[rf][0][q] + bF);
                hC[q] = f2bf(acc[rf][1][q] + bC);
                float gF = bf2f(hF[q]), gC = bf2f(hC[q]);
                sAF += gF; sBF += gF * gF;
                sAC += gC; sBC += gC * gC;
            }
            uint2 vF, vC;
            vF.x = (uint)hF[0] | ((uint)hF[1] << 16);
            vF.y = (uint)hF[2] | ((uint)hF[3] << 16);
            vC.x = (uint)hC[0] | ((uint)hC[1] << 16);
            vC.y = (uint)hC[2] | ((uint)hC[3] << 16);
            size_t base = ((((size_t)tile * 4 + w) * 12 + rf * 2) * 64 + lane) * 4;
            *(uint2*)&g[base] = vF;
            *(uint2*)&g[base + 256] = vC;   // c2=1 block is +64*4 ushorts
        }
    }

    // ------- end-of-kernel stats reduction -------
    // channel c holders: t = (c>>4)*64 + lg*16 + (c&15), lg = 0..3
    __syncthreads(); red[t] = sAF; __syncthreads();
    if (t < 64) {
        float s = 0.f;
#pragma unroll
        for (int g2 = 0; g2 < 4; g2++) s += red[(t >> 4) * 64 + g2 * 16 + (t & 15)];
        atomicAdd(&stats[t], s);
    }
    __syncthreads(); red[t] = sBF; __syncthreads();
    if (t < 64) {
        float s = 0.f;
#pragma unroll
        for (int g2 = 0; g2 < 4; g2++) s += red[(t >> 4) * 64 + g2 * 16 + (t & 15)];
        atomicAdd(&stats[128 + t], s);
    }
    __syncthreads(); red[t] = sAC; __syncthreads();
    if (t < 64) {
        float s = 0.f;
#pragma unroll
        for (int g2 = 0; g2 < 4; g2++) s += red[(t >> 4) * 64 + g2 * 16 + (t & 15)];
        atomicAdd(&stats[64 + t], s);
    }
    __syncthreads(); red[t] = sBC; __syncthreads();
    if (t < 64) {
        float s = 0.f;
#pragma unroll
        for (int g2 = 0; g2 < 4; g2++) s += red[(t >> 4) * 64 + g2 * 16 + (t & 15)];
        atomicAdd(&stats[192 + t], s);
    }
}

// ---------------- gated: read raw g, bn1 apply, gate, atom-sum via xor32 ----------------
#define GATED_GRID 2048
__launch_bounds__(256)
__global__ void gated_kernel(const ushort* __restrict__ g,
                             const float* __restrict__ sc1, const float* __restrict__ sh1,
                             float* __restrict__ summed, float* __restrict__ stats2) {
    __shared__ float red[256];
    const int t = threadIdx.x;
    const int lane = t & 63;
    const int w = t >> 6;
    const int l15 = lane & 15;
    const int lg = lane >> 4;

    const int chF = w * 16 + l15;
    const float scF = sc1[chF],      shF = sh1[chF];
    const float scC = sc1[chF + 64], shC = sh1[chF + 64];

    float s2a = 0.f, s2b = 0.f;

    for (int tile = blockIdx.x; tile < NTILES; tile += GATED_GRID) {
        float psum[4] = {0.f, 0.f, 0.f, 0.f};
#pragma unroll
        for (int rf = 0; rf < 6; rf++) {
            size_t base = ((((size_t)tile * 4 + w) * 12 + rf * 2) * 64 + lane) * 4;
            uint2 vF = *(const uint2*)&g[base];
            uint2 vC = *(const uint2*)&g[base + 256];
            ushort hF[4] = {(ushort)(vF.x & 0xffff), (ushort)(vF.x >> 16),
                            (ushort)(vF.y & 0xffff), (ushort)(vF.y >> 16)};
            ushort hC[4] = {(ushort)(vC.x & 0xffff), (ushort)(vC.x >> 16),
                            (ushort)(vC.y & 0xffff), (ushort)(vC.y >> 16)};
#pragma unroll
            for (int q = 0; q < 4; q++) {
                float gF = bf2f(hF[q]) * scF + shF;
                float gC = bf2f(hC[q]) * scC + shC;
                psum[q] += sigmoid_fast(gF) * softplus_fast(gC);
            }
        }
        // combine complementary j-halves: lane lg <-> lg^2 (same l15, same atoms)
#pragma unroll
        for (int q = 0; q < 4; q++)
            psum[q] += __shfl_xor(psum[q], 32, 64);
        if (lg < 2) {
            int atom0 = tile * TILE_ATOMS;
#pragma unroll
            for (int q = 0; q < 4; q++) {
                int a_loc = lg * 4 + q;
                float sm = psum[q];
                summed[(size_t)(atom0 + a_loc) * FF + chF] = sm;
                s2a += sm; s2b += sm * sm;
            }
        }
    }

    // bn2 stats reduction (same holder pattern; lg>=2 partials are zero)
    __syncthreads(); red[t] = s2a; __syncthreads();
    if (t < 64) {
        float s = 0.f;
#pragma unroll
        for (int g2 = 0; g2 < 4; g2++) s += red[(t >> 4) * 64 + g2 * 16 + (t & 15)];
        atomicAdd(&stats2[t], s);
    }
    __syncthreads(); red[t] = s2b; __syncthreads();
    if (t < 64) {
        float s = 0.f;
#pragma unroll
        for (int g2 = 0; g2 < 4; g2++) s += red[(t >> 4) * 64 + g2 * 16 + (t & 15)];
        atomicAdd(&stats2[64 + t], s);
    }
}

// ---------------- legacy R4 two-pass conv (ws fallback) ----------------
template <int PASS>
__launch_bounds__(256, 2)
__global__ void conv_mfma(const ushort* __restrict__ xb, const float* __restrict__ nbr_fea,
                          const int* __restrict__ nidx, const ushort* __restrict__ wpk_l,
                          const float* __restrict__ fcb_l,
                          float* __restrict__ stats,
                          const float* __restrict__ sc1, const float* __restrict__ sh1,
                          float* __restrict__ summed, float* __restrict__ stats2) {
    __shared__ __align__(16) ushort As[TILE_ROWS * 192];
    __shared__ int nb[TILE_ROWS];
    __shared__ float gacc[TILE_ATOMS * FF];
    __shared__ float red[256];

    const int t = threadIdx.x;
    const int lane = t & 63;
    const int w = t >> 6;
    const int l15 = lane & 15;
    const int lg = lane >> 4;

    bf16x8 bfrag[2][6];
#pragma unroll
    for (int c2 = 0; c2 < 2; c2++)
#pragma unroll
        for (int kk = 0; kk < 6; kk++)
            bfrag[c2][kk] = *(const bf16x8*)&wpk_l[((((w + 4 * c2) * 6 + kk) * 64 + lane) * 8)];

    const int chF = w * 16 + l15;
    const int chC = chF + 64;
    const float bF = fcb_l[chF], bC = fcb_l[chC];
    float scF = 0.f, shF = 0.f, scC = 0.f, shC = 0.f;
    if (PASS == 1) { scF = sc1[chF]; shF = sh1[chF]; scC = sc1[chC]; shC = sh1[chC]; }

    float sAF = 0.f, sBF = 0.f, sAC = 0.f, sBC = 0.f;
    float s2a = 0.f, s2b = 0.f;

    for (int tile = blockIdx.x; tile < NTILES; tile += gridDim.x) {
        const int ebase = tile * TILE_ROWS;
        __syncthreads();
        if (t < TILE_ROWS) nb[t] = nidx[ebase + t];
        if (PASS == 1) { gacc[t] = 0.f; gacc[256 + t] = 0.f; }
        __syncthreads();

#pragma unroll
        for (int e = t; e < TILE_ROWS * SLOTS; e += 256) {
            int row = e / SLOTS;
            int slot = e - row * SLOTS;
            uint4 val;
            if (slot < 16) {
                int a = (slot < 8) ? (tile * TILE_ATOMS + row / 12) : nb[row];
                val = *(const uint4*)&xb[a * 64 + (slot & 7) * 8];
            } else {
                int kb = (slot - 16) * 8;
                const float* src = nbr_fea + (size_t)(ebase + row) * NBR + kb;
                ushort h[8];
#pragma unroll
                for (int i = 0; i < 8; i++)
                    h[i] = (kb + i < NBR) ? f2bf(src[i]) : (ushort)0;
                val.x = (uint)h[0] | ((uint)h[1] << 16);
                val.y = (uint)h[2] | ((uint)h[3] << 16);
                val.z = (uint)h[4] | ((uint)h[5] << 16);
                val.w = (uint)h[6] | ((uint)h[7] << 16);
            }
            *(uint4*)&As[row * 192 + ((slot ^ (row & 7)) * 8)] = val;
        }
        __syncthreads();

        f32x4 acc[6][2];
#pragma unroll
        for (int rf = 0; rf < 6; rf++)
#pragma unroll
            for (int c2 = 0; c2 < 2; c2++) acc[rf][c2] = (f32x4){0.f, 0.f, 0.f, 0.f};

#pragma unroll
        for (int kk = 0; kk < 6; kk++) {
#pragma unroll
            for (int rf = 0; rf < 6; rf++) {
                int row = rf * 16 + l15;
                int slot = kk * 4 + lg;
                bf16x8 a = *(const bf16x8*)&As[row * 192 + ((slot ^ (row & 7)) * 8)];
                acc[rf][0] = __builtin_amdgcn_mfma_f32_16x16x32_bf16(a, bfrag[0][kk], acc[rf][0], 0, 0, 0);
                acc[rf][1] = __builtin_amdgcn_mfma_f32_16x16x32_bf16(a, bfrag[1][kk], acc[rf][1], 0, 0, 0);
            }
        }

        if (PASS == 0) {
#pragma unroll
            for (int rf = 0; rf < 6; rf++)
#pragma unroll
                for (int q = 0; q < 4; q++) {
                    float gF = acc[rf][0][q] + bF;
                    float gC = acc[rf][1][q] + bC;
                    sAF += gF; sBF += gF * gF;
                    sAC += gC; sBC += gC * gC;
                }
        } else {
#pragma unroll
            for (int rf = 0; rf < 6; rf++) {
                int r0 = rf * 16 + lg * 4;
                float p = 0.f;
#pragma unroll
                for (int q = 0; q < 4; q++) {
                    float gF = (acc[rf][0][q] + bF) * scF + shF;
                    float gC = (acc[rf][1][q] + bC) * scC + shC;
                    p += sigmoidf_(gF) * softplusf(gC);
                }
                atomicAdd(&gacc[(r0 / 12) * FF + chF], p);
            }
            __syncthreads();
#pragma unroll
            for (int rep = 0; rep < 2; rep++) {
                int idx = rep * 256 + t;
                int a = idx >> 6, c = idx & 63;
                float sm = gacc[idx];
                summed[(tile * TILE_ATOMS + a) * FF + c] = sm;
                s2a += sm; s2b += sm * sm;
            }
        }
    }

    if (PASS == 0) {
        __syncthreads(); red[t] = sAF; __syncthreads();
        if (t < 64) {
            float s = 0.f;
#pragma unroll
            for (int g2 = 0; g2 < 4; g2++) s += red[(t >> 4) * 64 + g2 * 16 + (t & 15)];
            atomicAdd(&stats[t], s);
        }
        __syncthreads(); red[t] = sBF; __syncthreads();
        if (t < 64) {
            float s = 0.f;
#pragma unroll
            for (int g2 = 0; g2 < 4; g2++) s += red[(t >> 4) * 64 + g2 * 16 + (t & 15)];
            atomicAdd(&stats[128 + t], s);
        }
        __syncthreads(); red[t] = sAC; __syncthreads();
        if (t < 64) {
            float s = 0.f;
#pragma unroll
            for (int g2 = 0; g2 < 4; g2++) s += red[(t >> 4) * 64 + g2 * 16 + (t & 15)];
            atomicAdd(&stats[64 + t], s);
        }
        __syncthreads(); red[t] = sBC; __syncthreads();
        if (t < 64) {
            float s = 0.f;
#pragma unroll
            for (int g2 = 0; g2 < 4; g2++) s += red[(t >> 4) * 64 + g2 * 16 + (t & 15)];
            atomicAdd(&stats[192 + t], s);
        }
    } else {
        __syncthreads(); red[t] = s2a; __syncthreads();
        if (t < 64) {
            float s = red[t] + red[64 + t] + red[128 + t] + red[192 + t];
            atomicAdd(&stats2[t], s);
        }
        __syncthreads(); red[t] = s2b; __syncthreads();
        if (t < 64) {
            float s = red[t] + red[64 + t] + red[128 + t] + red[192 + t];
            atomicAdd(&stats2[64 + t], s);
        }
    }
}

// ---------------- bn finalize ----------------
__global__ void fin1_kernel(const float* __restrict__ stats, const float* __restrict__ g,
                            const float* __restrict__ b, float* __restrict__ sc, float* __restrict__ sh) {
    int c = threadIdx.x;  // 128
    const float inv = 1.f / (float)(NN * MM);
    float mu = stats[c] * inv;
    float var = stats[128 + c] * inv - mu * mu;
    float s = rsqrtf(var + EPSV) * g[c];
    sc[c] = s;
    sh[c] = b[c] - mu * s;
}

__global__ void fin2_kernel(const float* __restrict__ stats2, const float* __restrict__ g,
                            const float* __restrict__ b, float* __restrict__ sc, float* __restrict__ sh) {
    int c = threadIdx.x;  // 64
    const float inv = 1.f / (float)NN;
    float mu = stats2[c] * inv;
    float var = stats2[64 + c] * inv - mu * mu;
    float s = rsqrtf(var + EPSV) * g[c];
    sc[c] = s;
    sh[c] = b[c] - mu * s;
}

// ---------------- x = softplus(x + bn2(summed)) ; refresh xb ----------------
__global__ void update_x_kernel(float* __restrict__ x, ushort* __restrict__ xb,
                                const float* __restrict__ summed,
                                const float* __restrict__ sc2, const float* __restrict__ sh2) {
    for (int idx = blockIdx.x * blockDim.x + threadIdx.x; idx < NN * FF;
         idx += gridDim.x * blockDim.x) {
        int c = idx & 63;
        float v = softplusf(x[idx] + summed[idx] * sc2[c] + sh2[c]);
        x[idx] = v;
        xb[idx] = f2bf(v);
    }
}

// ---------------- last layer: update_x fused with segment pooling ----------------
__global__ void update_x_pool_kernel(const float* __restrict__ x,
                                     const float* __restrict__ summed,
                                     const float* __restrict__ sc2, const float* __restrict__ sh2,
                                     const int* __restrict__ seg,
                                     float* __restrict__ csum, float* __restrict__ ccnt) {
    for (int idx = blockIdx.x * blockDim.x + threadIdx.x; idx < NN * FF;
         idx += gridDim.x * blockDim.x) {
        int i = idx >> 6;
        int c = idx & 63;
        float v = softplusf(x[idx] + summed[idx] * sc2[c] + sh2[c]);
        atomicAdd(&csum[seg[i] * FF + c], v);
        if (c == 0) atomicAdd(&ccnt[seg[i]], 1.f);
    }
}

// ---------------- per-crystal head ----------------
__global__ void head_kernel(const float* __restrict__ csum, const float* __restrict__ ccnt,
                            const float* __restrict__ c2fW, const float* __restrict__ c2fb,
                            const float* __restrict__ outW, const float* __restrict__ outb,
                            float* __restrict__ out) {
    __shared__ float pl[FF];
    __shared__ float red[HH];
    int c = blockIdx.x;
    int t = threadIdx.x;
    if (t < FF) {
        float cnt = fmaxf(ccnt[c], 1.f);
        pl[t] = softplusf(csum[c * FF + t] / cnt);
    }
    __syncthreads();
    float acc = c2fb[t];
    for (int f = 0; f < FF; f++) acc += pl[f] * c2fW[f * HH + t];
    red[t] = softplusf(acc) * outW[t];
    __syncthreads();
    for (int s = 64; s > 0; s >>= 1) {
        if (t < s) red[t] += red[t + s];
        __syncthreads();
    }
    if (t == 0) out[c] = red[0] + outb[0];
}

extern "C" void kernel_launch(void* const* d_in, const int* in_sizes, int n_in,
                              void* d_out, int out_size, void* d_ws, size_t ws_size,
                              hipStream_t stream) {
    const float* atom_fea = (const float*)d_in[0];
    const float* nbr_fea  = (const float*)d_in[1];
    const int*   nbr_idx  = (const int*)d_in[2];
    const int*   seg      = (const int*)d_in[3];
    const float* mask = (const float*)d_in[5];
    const float* embW = (const float*)d_in[6];
    const float* embb = (const float*)d_in[7];
    const float* fcW  = (const float*)d_in[8];
    const float* fcb  = (const float*)d_in[9];
    const float* bn1g = (const float*)d_in[10];
    const float* bn1b = (const float*)d_in[11];
    const float* bn2g = (const float*)d_in[12];
    const float* bn2b = (const float*)d_in[13];
    const float* c2fW = (const float*)d_in[14];
    const float* c2fb = (const float*)d_in[15];
    const float* outW = (const float*)d_in[16];
    const float* outb = (const float*)d_in[17];
    float* out = (float*)d_out;

    // ws layout (f32 region, then ushort region; ccnt adjacent to csum!)
    float* ws     = (float*)d_ws;
    float* x      = ws;                       // N*F
    float* summed = x + NN * FF;              // N*F
    float* csum   = summed + NN * FF;         // CC*FF
    float* ccnt   = csum + CC * FF;           // CC (+3 pad -> 3128)
    float* stats  = ccnt + 3128;              // 256
    float* stats2 = stats + 256;              // 128
    float* sc1    = stats2 + 128;             // 128
    float* sh1    = sc1 + 128;                // 128
    float* sc2    = sh1 + 128;                // 64
    float* sh2    = sc2 + 64;                 // 64
    ushort* xb    = (ushort*)(sh2 + 64);      // N*F bf16
    ushort* wpk   = xb + NN * FF;             // 3 * WPK_L
    ushort* nbrb  = wpk + 3 * WPK_L;          // N*M*64 bf16
    ushort* gbuf  = nbrb + (size_t)NN * MM * 64;  // NTILES*GRAW_TILE bf16 (raw layout)

    const size_t need_full =
        (size_t)((char*)(gbuf + (size_t)NTILES * GRAW_TILE) - (char*)d_ws);
    const bool full = (ws_size >= need_full);

    packW_kernel<<<144, 64, 0, stream>>>(fcW, wpk);
    embed_kernel<<<2048, 256, 0, stream>>>(atom_fea, mask, embW, embb, x, xb);
    if (full) prepack_nbr<<<4096, 256, 0, stream>>>(nbr_fea, nbrb);
    hipMemsetAsync(csum, 0, (CC * FF + CC) * sizeof(float), stream);

    for (int l = 0; l < NCONV; l++) {
        const ushort* wpk_l = wpk + l * WPK_L;
        hipMemsetAsync(stats, 0, (256 + 128) * sizeof(float), stream);
        if (full) {
            conv_g<<<2048, 256, 0, stream>>>(xb, nbrb, nbr_idx, wpk_l, fcb + l * GG,
                                             stats, gbuf);
            fin1_kernel<<<1, 128, 0, stream>>>(stats, bn1g + l * GG, bn1b + l * GG, sc1, sh1);
            gated_kernel<<<GATED_GRID, 256, 0, stream>>>(gbuf, sc1, sh1, summed, stats2);
        } else {
            conv_mfma<0><<<2048, 256, 0, stream>>>(xb, nbr_fea, nbr_idx, wpk_l, fcb + l * GG,
                                                   stats, nullptr, nullptr, nullptr, nullptr);
            fin1_kernel<<<1, 128, 0, stream>>>(stats, bn1g + l * GG, bn1b + l * GG, sc1, sh1);
            conv_mfma<1><<<2048, 256, 0, stream>>>(xb, nbr_fea, nbr_idx, wpk_l, fcb + l * GG,
                                                   nullptr, sc1, sh1, summed, stats2);
        }
        fin2_kernel<<<1, 64, 0, stream>>>(stats2, bn2g + l * FF, bn2b + l * FF, sc2, sh2);
        if (l < NCONV - 1) {
            update_x_kernel<<<2048, 256, 0, stream>>>(x, xb, summed, sc2, sh2);
        } else {
            update_x_pool_kernel<<<2048, 256, 0, stream>>>(x, summed, sc2, sh2,
                                                           seg, csum, ccnt);
        }
    }

    head_kernel<<<CC, 128, 0, stream>>>(csum, ccnt, c2fW, c2fb, outW, outb, out);
}